// Round 11
// baseline (400.908 us; speedup 1.0000x reference)
//
#include <hip/hip_runtime.h>
#include <hip/hip_bf16.h>

#define DD 128
#define D3 (DD*DD*DD)      // 2097152
#define NB 8               // batch
#define NV 65536           // points
#define HID 256
#define LAT 128

// bricks: 32x8x4 voxels -> 4 x 16 x 32 = 2048 per batch, 16384 total
#define NBIN 2048
#define NBIN_TOT (NBIN*NB) // 16384

// round-to-nearest-even f32 -> bf16, returned as the (exactly representable) f32 value
__device__ __forceinline__ float rbf(float x) {
    unsigned u = __float_as_uint(x);
    unsigned r = (u + 0x7fffu + ((u >> 16) & 1u)) & 0xFFFF0000u;
    return __uint_as_float(r);
}

// async global->LDS: 16B per lane, dest = wave-uniform base + lane*16 (HW-applied)
__device__ __forceinline__ void gload16(const float4* src, void* ldst) {
    __builtin_amdgcn_global_load_lds(
        (const __attribute__((address_space(1))) void*)src,
        (__attribute__((address_space(3))) void*)ldst, 16, 0, 0);
}

// ====== heads + in-block MLP + pipelined streaming GEMV ======
__global__ __launch_bounds__(256) void k_heads(
    const float* __restrict__ x,
    const float* __restrict__ w0, const float* __restrict__ b0,
    const float* __restrict__ w1, const float* __restrict__ b1,
    const float* __restrict__ w2, const float* __restrict__ b2,
    const float* __restrict__ w3, const float* __restrict__ b3,
    const float* __restrict__ w4, const float* __restrict__ b4,
    const float* __restrict__ wc, const float* __restrict__ bc,
    const float* __restrict__ wv, const float* __restrict__ bv,
    const float* __restrict__ coords0, const float* __restrict__ values0,
    float4* __restrict__ posval)
{
    __shared__ float  xsT[LAT * NB];       // 4 KB  [k][b] of x
    __shared__ float  hbA[HID * NB];       // 8 KB  ping
    __shared__ float  hbB[HID * NB];       // 8 KB  pong
    __shared__ float  hsT[HID * NB];       // 8 KB  final h4 [k][b]
    __shared__ float4 wcs4[4][768];        // 48 KB: 4 bufs x (4 k-rows x 192 f4)
    __shared__ float4 wvs4[4][256];        // 16 KB: 4 bufs x (4 k-rows x 64 f4)

    const int tid  = threadIdx.x;
    const int blk  = blockIdx.x;
    const int lane = tid & 63;
    const int wid  = tid >> 6;
    const int pt   = blk * 256 + tid;

    const float4* wc4 = reinterpret_cast<const float4*>(wc);
    const float4* wv4 = reinterpret_cast<const float4*>(wv);

    // per-thread stage-chunk geometry (stage = 4 k-rows; 12 wc chunks + 4 wv chunks
    // of 64 float4 each; wave w handles wc chunks {w, w+4, w+8} and wv chunk w)
    size_t wcbase[3]; int wcdst[3];
    #pragma unroll
    for (int u = 0; u < 3; ++u) {
        int c = wid + 4 * u;                   // chunk id 0..11 (wave-uniform)
        int r = c / 3, p = c % 3;              // k-row in stage, part in row
        wcbase[u] = (size_t)r * 49152 + (size_t)blk * 192 + p * 64 + lane;
        wcdst[u] = __builtin_amdgcn_readfirstlane(c * 1024);   // byte off in buffer
    }
    const size_t wvbase = (size_t)wid * 16384 + (size_t)blk * 64 + lane;
    const int   wvdst  = __builtin_amdgcn_readfirstlane(wid * 1024);

    // ---------------- Phase A: in-block MLP (identical numerics to round 10) -------
    for (int i = tid; i < NB * LAT; i += 256) {
        int b = i >> 7, k = i & 127;
        xsT[k * 8 + b] = rbf(x[i]);
    }
    __syncthreads();

    float a[NB];
    const float4* xsp = reinterpret_cast<const float4*>(xsT);

    #pragma unroll
    for (int b = 0; b < NB; ++b) a[b] = 0.f;
    #pragma unroll 8
    for (int k = 0; k < LAT; ++k) {
        float wk = rbf(w0[k * HID + tid]);
        float4 hA_ = xsp[k * 2], hB_ = xsp[k * 2 + 1];
        float hb[8] = {hA_.x, hA_.y, hA_.z, hA_.w, hB_.x, hB_.y, hB_.z, hB_.w};
        #pragma unroll
        for (int b = 0; b < NB; ++b) a[b] = fmaf(hb[b], wk, a[b]);
    }
    {
        float bb = rbf(b0[tid]);
        #pragma unroll
        for (int b = 0; b < NB; ++b) {
            float t = rbf(a[b]);
            t = rbf(t + bb);
            t = rbf(30.0f * t);
            hbA[tid * 8 + b] = rbf(sinf(t));
        }
    }
    __syncthreads();

    {
        const float* Ws[3] = {w1, w2, w3};
        const float* Bs[3] = {b1, b2, b3};
        float* cur = hbA;
        float* nxt = hbB;
        for (int L = 0; L < 3; ++L) {
            const float* w = Ws[L];
            const float4* hp = reinterpret_cast<const float4*>(cur);
            #pragma unroll
            for (int b = 0; b < NB; ++b) a[b] = 0.f;
            #pragma unroll 8
            for (int k = 0; k < HID; ++k) {
                float wk = rbf(w[k * HID + tid]);
                float4 hA_ = hp[k * 2], hB_ = hp[k * 2 + 1];
                float hb[8] = {hA_.x, hA_.y, hA_.z, hA_.w, hB_.x, hB_.y, hB_.z, hB_.w};
                #pragma unroll
                for (int b = 0; b < NB; ++b) a[b] = fmaf(hb[b], wk, a[b]);
            }
            float bb = rbf(Bs[L][tid]);
            #pragma unroll
            for (int b = 0; b < NB; ++b) {
                float t = rbf(a[b]);
                t = rbf(t + bb);
                float r = rbf(cur[tid * 8 + b] + t);
                nxt[tid * 8 + b] = rbf(sinf(r));
            }
            __syncthreads();
            float* tmp = cur; cur = nxt; nxt = tmp;
        }
        const float4* hp = reinterpret_cast<const float4*>(cur);
        #pragma unroll
        for (int b = 0; b < NB; ++b) a[b] = 0.f;
        #pragma unroll 8
        for (int k = 0; k < HID; ++k) {
            float wk = rbf(w4[k * HID + tid]);
            float4 hA_ = hp[k * 2], hB_ = hp[k * 2 + 1];
            float hb[8] = {hA_.x, hA_.y, hA_.z, hA_.w, hB_.x, hB_.y, hB_.z, hB_.w};
            #pragma unroll
            for (int b = 0; b < NB; ++b) a[b] = fmaf(hb[b], wk, a[b]);
        }
        float bb = rbf(b4[tid]);
        #pragma unroll
        for (int b = 0; b < NB; ++b) {
            float t = rbf(a[b]);
            hsT[tid * 8 + b] = rbf(t + bb);
        }
    }

    // ---------------- Phase B: depth-3 pipelined staged GEMV -----------------------
    // stage s (0..63) covers k-rows s*4..s*4+3. STAGE issues 4 global_load_lds per
    // wave; counted vmcnt keeps 2 stages in flight; raw s_barrier (no vmcnt drain).
    #define STAGE(s_) {                                                              \
        const int buf_ = (s_) & 3;                                                   \
        const size_t so_ = (size_t)(s_) * 196608;                                    \
        gload16(wc4 + wcbase[0] + so_, (char*)&wcs4[buf_][0] + wcdst[0]);            \
        gload16(wc4 + wcbase[1] + so_, (char*)&wcs4[buf_][0] + wcdst[1]);            \
        gload16(wc4 + wcbase[2] + so_, (char*)&wcs4[buf_][0] + wcdst[2]);            \
        gload16(wv4 + wvbase + (size_t)(s_) * 65536, (char*)&wvs4[buf_][0] + wvdst); \
    }

    float acc[4][8];
    #pragma unroll
    for (int c = 0; c < 4; ++c)
        #pragma unroll
        for (int b = 0; b < NB; ++b) acc[c][b] = 0.f;

    const float4* h4v = reinterpret_cast<const float4*>(hsT);

    // drain MLP-era counters so counted vmcnt arithmetic is exact; also flush hsT
    asm volatile("s_waitcnt vmcnt(0) lgkmcnt(0)" ::: "memory");
    STAGE(0); STAGE(1); STAGE(2);

    for (int s = 0; s < 64; ++s) {
        if (s < 62)       asm volatile("s_waitcnt vmcnt(8)" ::: "memory");
        else if (s == 62) asm volatile("s_waitcnt vmcnt(4)" ::: "memory");
        else              asm volatile("s_waitcnt vmcnt(0)" ::: "memory");
        __builtin_amdgcn_s_barrier();       // all waves' stage-s chunks now in LDS
        asm volatile("" ::: "memory");
        if (s < 61) STAGE(s + 3);

        const int buf = s & 3;
        const float* wcsF = reinterpret_cast<const float*>(&wcs4[buf][0]);
        const float* wvsF = reinterpret_cast<const float*>(&wvs4[buf][0]);
        #pragma unroll
        for (int r = 0; r < 4; ++r) {
            const int k = s * 4 + r;
            float c0 = wcsF[r * 768 + 3 * tid];
            float c1 = wcsF[r * 768 + 3 * tid + 1];
            float c2 = wcsF[r * 768 + 3 * tid + 2];
            float vv = wvsF[r * 256 + tid];
            float4 hA_ = h4v[k * 2], hB_ = h4v[k * 2 + 1];
            float hb[8] = {hA_.x, hA_.y, hA_.z, hA_.w, hB_.x, hB_.y, hB_.z, hB_.w};
            #pragma unroll
            for (int b = 0; b < NB; ++b) {
                acc[0][b] = fmaf(hb[b], c0, acc[0][b]);
                acc[1][b] = fmaf(hb[b], c1, acc[1][b]);
                acc[2][b] = fmaf(hb[b], c2, acc[2][b]);
                acc[3][b] = fmaf(hb[b], vv, acc[3][b]);
            }
        }
        asm volatile("" ::: "memory");      // keep compute inside its stage window
    }
    #undef STAGE

    // epilogue
    const float factor = 0.5f * DD;
    const float cx = coords0[3 * pt], cy = coords0[3 * pt + 1], cz = coords0[3 * pt + 2];
    const float bx = bc[3 * pt], by = bc[3 * pt + 1], bz = bc[3 * pt + 2];
    const float v0 = values0[pt], bvv = bv[pt];
    #pragma unroll
    for (int b = 0; b < NB; ++b) {
        float px = factor * (cx + (acc[0][b] + bx)) + factor;
        float py = factor * (cy + (acc[1][b] + by)) + factor;
        float pz = factor * (cz + (acc[2][b] + bz)) + factor;
        float val = fmaxf(v0 + (acc[3][b] + bvv), 0.f);
        posval[(size_t)b * NV + pt] = make_float4(px, py, pz, val);
    }
}

// ----------------------------- binning helpers -------------------------------------
__device__ __forceinline__ bool point_base(float4 q, int& ix, int& iy, int& iz) {
    if (q.w == 0.f) return false;
    ix = (int)floorf(q.x); iy = (int)floorf(q.y); iz = (int)floorf(q.z);
    return ix >= -1 && ix <= 127 && iy >= -1 && iy <= 127 && iz >= -1 && iz <= 127;
}

__device__ __forceinline__ void brick_span(int ix, int iy, int iz,
                                           int& bx0, int& bx1, int& by0, int& by1,
                                           int& bz0, int& bz1) {
    bx0 = (ix < 0 ? 0 : ix) >> 5;  bx1 = (ix + 1 > 127 ? 127 : ix + 1) >> 5;
    by0 = (iy < 0 ? 0 : iy) >> 3;  by1 = (iy + 1 > 127 ? 127 : iy + 1) >> 3;
    bz0 = (iz < 0 ? 0 : iz) >> 2;  bz1 = (iz + 1 > 127 ? 127 : iz + 1) >> 2;
}

// --------------- k_count: LDS histogram of (duplicated) entries per brick ----------
__global__ __launch_bounds__(256) void k_count(const float4* __restrict__ posval,
                                               unsigned* __restrict__ binCount)
{
    __shared__ unsigned hist[NBIN];
    const int tid = threadIdx.x;
    const int batch = blockIdx.x >> 5;
    const size_t base = (size_t)batch * NV + (blockIdx.x & 31) * 2048;
    for (int i = tid; i < NBIN; i += 256) hist[i] = 0;
    __syncthreads();
    #pragma unroll
    for (int j = 0; j < 8; ++j) {
        float4 q = posval[base + j * 256 + tid];
        int ix, iy, iz;
        if (point_base(q, ix, iy, iz)) {
            int bx0, bx1, by0, by1, bz0, bz1;
            brick_span(ix, iy, iz, bx0, bx1, by0, by1, bz0, bz1);
            for (int bz = bz0; bz <= bz1; ++bz)
                for (int by = by0; by <= by1; ++by)
                    for (int bx = bx0; bx <= bx1; ++bx)
                        atomicAdd(&hist[(bz * 16 + by) * 4 + bx], 1u);
        }
    }
    __syncthreads();
    for (int i = tid; i < NBIN; i += 256) {
        unsigned c = hist[i];
        if (c) atomicAdd(&binCount[batch * NBIN + i], c);
    }
}

// --------------- k_scan: exclusive scan over 16384 bins (single block) -------------
__global__ __launch_bounds__(1024) void k_scan(const unsigned* __restrict__ cnt,
                                               unsigned* __restrict__ start,
                                               unsigned* __restrict__ cursor)
{
    __shared__ unsigned partial[1024];
    const int t = threadIdx.x;
    const int base = t * 16;
    unsigned s = 0;
    #pragma unroll
    for (int j = 0; j < 16; ++j) s += cnt[base + j];
    partial[t] = s;
    __syncthreads();
    for (int off = 1; off < 1024; off <<= 1) {
        unsigned mine = partial[t];
        unsigned add = (t >= off) ? partial[t - off] : 0u;
        __syncthreads();
        partial[t] = mine + add;
        __syncthreads();
    }
    unsigned run = (t > 0) ? partial[t - 1] : 0u;
    #pragma unroll
    for (int j = 0; j < 16; ++j) {
        start[base + j] = run;
        cursor[base + j] = run;
        run += cnt[base + j];
    }
    if (t == 1023) start[NBIN_TOT] = partial[1023];
}

// -------- k_scatter: copy each point into every touched brick's contiguous range ----
__global__ __launch_bounds__(256) void k_scatter(const float4* __restrict__ posval,
                                                 unsigned* __restrict__ binCursor,
                                                 float4* __restrict__ sorted)
{
    __shared__ unsigned hist[NBIN];
    __shared__ unsigned bbase[NBIN];
    const int tid = threadIdx.x;
    const int batch = blockIdx.x >> 5;
    const size_t base = (size_t)batch * NV + (blockIdx.x & 31) * 2048;
    for (int i = tid; i < NBIN; i += 256) hist[i] = 0;
    __syncthreads();

    float4 q[8];
    #pragma unroll
    for (int j = 0; j < 8; ++j) {
        q[j] = posval[base + j * 256 + tid];
        int ix, iy, iz;
        if (point_base(q[j], ix, iy, iz)) {
            int bx0, bx1, by0, by1, bz0, bz1;
            brick_span(ix, iy, iz, bx0, bx1, by0, by1, bz0, bz1);
            for (int bz = bz0; bz <= bz1; ++bz)
                for (int by = by0; by <= by1; ++by)
                    for (int bx = bx0; bx <= bx1; ++bx)
                        atomicAdd(&hist[(bz * 16 + by) * 4 + bx], 1u);
        }
    }
    __syncthreads();
    for (int i = tid; i < NBIN; i += 256) {
        unsigned c = hist[i];
        bbase[i] = c ? atomicAdd(&binCursor[batch * NBIN + i], c) : 0u;
    }
    __syncthreads();
    for (int i = tid; i < NBIN; i += 256) hist[i] = 0;
    __syncthreads();
    #pragma unroll
    for (int j = 0; j < 8; ++j) {
        int ix, iy, iz;
        if (point_base(q[j], ix, iy, iz)) {
            int bx0, bx1, by0, by1, bz0, bz1;
            brick_span(ix, iy, iz, bx0, bx1, by0, by1, bz0, bz1);
            for (int bz = bz0; bz <= bz1; ++bz)
                for (int by = by0; by <= by1; ++by)
                    for (int bx = bx0; bx <= bx1; ++bx) {
                        int bin = (bz * 16 + by) * 4 + bx;
                        unsigned r = atomicAdd(&hist[bin], 1u);
                        sorted[bbase[bin] + r] = q[j];
                    }
        }
    }
}

// -------- k_binsplat: one block per 32x8x4 brick; exact list; LDS accumulate -------
__global__ __launch_bounds__(256) void k_binsplat(const float4* __restrict__ sorted,
                                                  const unsigned* __restrict__ binStart,
                                                  float* __restrict__ grid)
{
    __shared__ float brick[4 * 8 * 32];
    const int tid = threadIdx.x;
    const int bid = blockIdx.x;
    const int bx = bid & 3;
    const int by = (bid >> 2) & 15;
    const int bz = (bid >> 6) & 31;
    const int batch = bid >> 11;
    const int x0 = bx << 5, y0 = by << 3, z0 = bz << 2;

    const unsigned s = binStart[bid], e = binStart[bid + 1];

    const int vx4 = tid & 7, cy = (tid >> 3) & 7, cz = tid >> 6;
    const size_t o = (size_t)batch * D3 + (size_t)(z0 + cz) * (DD * DD)
                   + (size_t)(y0 + cy) * DD + x0 + vx4 * 4;

    if (s == e) {
        *reinterpret_cast<float4*>(grid + o) = make_float4(0.f, 0.f, 0.f, 0.f);
        return;
    }

    for (int i = tid; i < 1024; i += 256) brick[i] = 0.f;
    __syncthreads();

    for (unsigned i = s + tid; i < e; i += 256) {
        float4 q = sorted[i];
        float fx = floorf(q.x), fy = floorf(q.y), fz = floorf(q.z);
        int vx = (int)fx - x0, vy = (int)fy - y0, vz = (int)fz - z0;
        float gx = q.x - fx, gy = q.y - fy, gz = q.z - fz;
        float wx0 = 1.f - gx, wy0 = 1.f - gy, wz0 = 1.f - gz;
        #pragma unroll
        for (int oz = 0; oz < 2; ++oz)
        #pragma unroll
        for (int oy = 0; oy < 2; ++oy)
        #pragma unroll
        for (int ox = 0; ox < 2; ++ox) {
            int cxx = vx + ox, cyy = vy + oy, czz = vz + oz;
            if ((unsigned)cxx < 32u && (unsigned)cyy < 8u && (unsigned)czz < 4u) {
                float w = ((ox ? gx : wx0) * (oy ? gy : wy0)) * (oz ? gz : wz0);
                atomicAdd(&brick[(czz * 8 + cyy) * 32 + cxx], q.w * w);
            }
        }
    }
    __syncthreads();

    *reinterpret_cast<float4*>(grid + o) =
        *reinterpret_cast<const float4*>(&brick[(cz * 8 + cy) * 32 + vx4 * 4]);
}

// ------------------------- separable 7-tap gaussian blur (pencil) ------------------
__global__ __launch_bounds__(256) void k_blur(const float* __restrict__ in,
                                              float* __restrict__ out, int shift)
{
    const long i = (long)blockIdx.x * 256 + threadIdx.x;
    const int p = (int)((i >> shift) & (DD - 1));

    const double e1 = 0.6065306597126334, e2 = 0.1353352832366127, e3 = 0.011108996538242306;
    const double s = 1.0 + 2.0 * (e1 + e2 + e3);
    const float kw[7] = {(float)(e3 / s), (float)(e2 / s), (float)(e1 / s), (float)(1.0 / s),
                         (float)(e1 / s), (float)(e2 / s), (float)(e3 / s)};

    float acc = 0.f;
    #pragma unroll
    for (int j = -3; j <= 3; ++j) {
        int q = p + j;
        if (q >= 0 && q < DD)
            acc = fmaf(kw[j + 3], in[i + ((long)j << shift)], acc);
    }
    out[i] = acc;
}

// ------------------ fused y+x blur: 32-row y-strips per (batch, z) -----------------
__global__ __launch_bounds__(256) void k_blur_yx(const float* __restrict__ in,
                                                 float* __restrict__ out)
{
    __shared__ float sin_[38 * 128];
    __shared__ float sy[32 * 128];

    const double e1 = 0.6065306597126334, e2 = 0.1353352832366127, e3 = 0.011108996538242306;
    const double ss = 1.0 + 2.0 * (e1 + e2 + e3);
    const float kw[7] = {(float)(e3 / ss), (float)(e2 / ss), (float)(e1 / ss), (float)(1.0 / ss),
                         (float)(e1 / ss), (float)(e2 / ss), (float)(e3 / ss)};

    const int tid = threadIdx.x;
    const int bid = blockIdx.x;
    const int ytile = bid & 3;
    const int z = (bid >> 2) & 127;
    const int batch = bid >> 9;
    const int y0 = ytile << 5;
    const size_t slab = (size_t)batch * D3 + (size_t)z * (DD * DD);

    for (int i = tid; i < 38 * 128; i += 256) {
        int row = i >> 7, xx = i & 127;
        int gy = y0 + row - 3;
        sin_[i] = (gy >= 0 && gy < DD) ? in[slab + (size_t)gy * DD + xx] : 0.f;
    }
    __syncthreads();

    for (int i = tid; i < 32 * 128; i += 256) {
        int r = i >> 7, xx = i & 127;
        float acc = 0.f;
        #pragma unroll
        for (int j = 0; j < 7; ++j)
            acc = fmaf(kw[j], sin_[(r + j) * 128 + xx], acc);
        sy[i] = acc;
    }
    __syncthreads();

    for (int i = tid; i < 32 * 128; i += 256) {
        int r = i >> 7, xx = i & 127;
        float acc = 0.f;
        #pragma unroll
        for (int j = -3; j <= 3; ++j) {
            int qx = xx + j;
            if (qx >= 0 && qx < DD)
                acc = fmaf(kw[j + 3], sy[r * 128 + qx], acc);
        }
        out[slab + (size_t)(y0 + r) * DD + xx] = acc;
    }
}

extern "C" void kernel_launch(void* const* d_in, const int* in_sizes, int n_in,
                              void* d_out, int out_size, void* d_ws, size_t ws_size,
                              hipStream_t stream) {
    const float* x   = (const float*)d_in[0];
    const float* w0  = (const float*)d_in[1];
    const float* b0  = (const float*)d_in[2];
    const float* w1  = (const float*)d_in[3];
    const float* b1  = (const float*)d_in[4];
    const float* w2  = (const float*)d_in[5];
    const float* b2  = (const float*)d_in[6];
    const float* w3  = (const float*)d_in[7];
    const float* b3  = (const float*)d_in[8];
    const float* w4  = (const float*)d_in[9];
    const float* b4  = (const float*)d_in[10];
    const float* wc  = (const float*)d_in[11];
    const float* bc  = (const float*)d_in[12];
    const float* wv  = (const float*)d_in[13];
    const float* bv  = (const float*)d_in[14];
    const float* c0  = (const float*)d_in[15];
    const float* v0  = (const float*)d_in[16];

    float* out = (float*)d_out;
    float4* posval = (float4*)d_out;                  // [NB][NV] float4 = 8 MiB
    float4* sorted = (float4*)d_ws;
    unsigned* binCount  = (unsigned*)((char*)d_ws + (48u << 20));
    unsigned* binStart  = binCount + NBIN_TOT;
    unsigned* binCursor = binStart + NBIN_TOT + 1;

    hipMemsetAsync(binCount, 0, NBIN_TOT * sizeof(unsigned), stream);

    k_heads<<<NV / 256, 256, 0, stream>>>(x, w0, b0, w1, b1, w2, b2, w3, b3, w4, b4,
                                          wc, bc, wv, bv, c0, v0, posval);

    k_count<<<256, 256, 0, stream>>>(posval, binCount);
    k_scan<<<1, 1024, 0, stream>>>(binCount, binStart, binCursor);
    k_scatter<<<256, 256, 0, stream>>>(posval, binCursor, sorted);
    k_binsplat<<<NBIN_TOT, 256, 0, stream>>>(sorted, binStart, out);

    const int nblk = (NB * D3) / 256;
    k_blur<<<nblk, 256, 0, stream>>>(out, (float*)d_ws, 14);
    k_blur_yx<<<NB * 512, 256, 0, stream>>>((float*)d_ws, out);
}

// Round 12
// 355.766 us; speedup vs baseline: 1.1269x; 1.1269x over previous
//
#include <hip/hip_runtime.h>
#include <hip/hip_bf16.h>

#define DD 128
#define D3 (DD*DD*DD)      // 2097152
#define NB 8               // batch
#define NV 65536           // points
#define HID 256
#define LAT 128

// bricks: 32x8x4 voxels -> 2048 per batch, 16384 total
#define NBIN 2048
#define NBIN_TOT (NBIN*NB)

// round-to-nearest-even f32 -> bf16, returned as the (exactly representable) f32 value
__device__ __forceinline__ float rbf(float x) {
    unsigned u = __float_as_uint(x);
    unsigned r = (u + 0x7fffu + ((u >> 16) & 1u)) & 0xFFFF0000u;
    return __uint_as_float(r);
}

// ---------------- SIREN layer: one kernel per layer, 4 blocks x 256 threads --------
// (round-6 code verbatim: proven 69us chain, absmax-passing numerics)
template<int K, int MODE>
__global__ __launch_bounds__(256) void k_layer(
    const float* __restrict__ in, const float* __restrict__ w,
    const float* __restrict__ bias, float* __restrict__ outp)
{
    __shared__ float in_s[NB * K];
    __shared__ float part[4 * 64 * 8];
    const int tid = threadIdx.x;
    for (int i = tid; i < NB * K; i += 256) in_s[i] = rbf(in[i]);
    __syncthreads();

    const int cl = tid & 63;
    const int ks = tid >> 6;
    const int col = blockIdx.x * 64 + cl;

    float acc[NB];
    #pragma unroll
    for (int b = 0; b < NB; ++b) acc[b] = 0.f;

    const int k0 = ks * (K / 4);
    #pragma unroll 8
    for (int k = k0; k < k0 + K / 4; ++k) {
        float wk = rbf(w[k * HID + col]);
        #pragma unroll
        for (int b = 0; b < NB; ++b) acc[b] = fmaf(in_s[b * K + k], wk, acc[b]);
    }

    float* pp = part + (ks * 64 + cl) * 8;
    #pragma unroll
    for (int b = 0; b < NB; ++b) pp[b] = acc[b];
    __syncthreads();

    #pragma unroll
    for (int u = 0; u < 2; ++u) {
        const int idx = tid * 2 + u;
        const int c2 = idx >> 3, b = idx & 7;
        const int gcol = blockIdx.x * 64 + c2;
        float s = (part[(0 * 64 + c2) * 8 + b] + part[(1 * 64 + c2) * 8 + b])
                + (part[(2 * 64 + c2) * 8 + b] + part[(3 * 64 + c2) * 8 + b]);
        float t = rbf(s);
        t = rbf(t + rbf(bias[gcol]));
        if (MODE == 0) {
            t = rbf(30.0f * t);
            t = rbf(sinf(t));
        } else if (MODE == 1) {
            float r = rbf(in_s[b * K + gcol] + t);
            t = rbf(sinf(r));
        }
        outp[b * HID + gcol] = t;
    }
}

// ------ heads: staged streaming GEMV, 64 pts/block, k-split 4, reg-staged dbuf -----
// 1024 blocks x 256 threads (4 blocks/CU). Stage = 8 k-rows (2 per slice):
// wc 6KB + wv 2KB staged per buffer; loads for stage s+2 issued BEFORE compute(s)
// into REGISTERS (no LDS hazard), written to LDS after the post-compute barrier ->
// each __syncthreads vmcnt-drain finds loads aged by a full compute phase.
#define PSTR 17
__global__ __launch_bounds__(256, 4) void k_heads(
    const float* __restrict__ h4,
    const float* __restrict__ wc, const float* __restrict__ bc,
    const float* __restrict__ wv, const float* __restrict__ bv,
    const float* __restrict__ coords0, const float* __restrict__ values0,
    float4* __restrict__ posval)
{
    __shared__ float hsT[HID * NB];                         // 8 KB [k][b]
    __shared__ __align__(16) char uni[4 * 64 * PSTR * 4];   // 17.4 KB union
    float4 (*buf)[512] = reinterpret_cast<float4(*)[512]>(uni);  // dbuf 2x8KB
    float* part = reinterpret_cast<float*>(uni);                 // epilogue overlay

    const int tid = threadIdx.x;
    const int blk = blockIdx.x;          // 64 points per block
    const int p   = tid & 63;            // point-in-block (lane)
    const int ks  = tid >> 6;            // k-slice = wave id (uniform)

    for (int i = tid; i < NB * HID; i += 256) {
        int b = i >> 8, k = i & 255;
        hsT[k * 8 + b] = h4[b * HID + k];
    }

    // slot geometry: stage has 512 f4 slots: 0..383 wc ([row r=t/48][c=t%48], row
    // r -> slice r>>1, j=r&1, global k-row g = (r>>1)*64 + (r&1) + 2s), 384..511 wv.
    // thread t owns slots {t, t+256}. slot1 is wc for t<128 (waves 0-1), wv else.
    const float4* wc4 = reinterpret_cast<const float4*>(wc);
    const float4* wv4 = reinterpret_cast<const float4*>(wv);

    size_t base0, base1, step1;
    {
        int r = tid / 48, c = tid - r * 48;
        base0 = (size_t)((r >> 1) * 64 + (r & 1)) * 49152 + (size_t)blk * 48 + c;
    }
    const float4* src1;
    if (tid < 128) {
        int t1 = tid + 256;
        int r = t1 / 48, c = t1 - r * 48;
        base1 = (size_t)((r >> 1) * 64 + (r & 1)) * 49152 + (size_t)blk * 48 + c;
        src1 = wc4; step1 = 2 * 49152;
    } else {
        int u = tid - 128;
        int r = u >> 4, c = u & 15;
        base1 = (size_t)((r >> 1) * 64 + (r & 1)) * 16384 + (size_t)blk * 16 + c;
        src1 = wv4; step1 = 2 * 16384;
    }
    const size_t step0 = 2 * 49152;
    const int d0 = tid, d1 = tid + 256;

    float acc[4][8];                     // [x,y,z,val][batch]
    #pragma unroll
    for (int c = 0; c < 4; ++c)
        #pragma unroll
        for (int b = 0; b < NB; ++b) acc[c][b] = 0.f;

    const float4* h4v = reinterpret_cast<const float4*>(hsT);

    // prologue: stage 0 -> buf0; stage 1 held in R
    float4 R0 = wc4[base0];
    float4 R1 = src1[base1];
    buf[0][d0] = R0; buf[0][d1] = R1;
    R0 = wc4[base0 + step0];
    R1 = src1[base1 + step1];
    __syncthreads();                     // hsT + buf0 visible

    float4 R0n, R1n;
    for (int s = 0; s < 32; ++s) {
        if (s + 2 < 32) {                // issue s+2 BEFORE compute -> latency covered
            R0n = wc4[base0 + (size_t)(s + 2) * step0];
            R1n = src1[base1 + (size_t)(s + 2) * step1];
        }
        const int bi = s & 1;
        const float* wcsF = reinterpret_cast<const float*>(&buf[bi][0]);
        const float* wvsF = reinterpret_cast<const float*>(&buf[bi][384]);
        #pragma unroll
        for (int j = 0; j < 2; ++j) {
            const int r = ks * 2 + j;
            const int k = ks * 64 + 2 * s + j;
            float c0 = wcsF[r * 192 + 3 * p];
            float c1 = wcsF[r * 192 + 3 * p + 1];
            float c2 = wcsF[r * 192 + 3 * p + 2];
            float vv = wvsF[r * 64 + p];
            float4 hA_ = h4v[k * 2], hB_ = h4v[k * 2 + 1];   // uniform broadcast
            float hb[8] = {hA_.x, hA_.y, hA_.z, hA_.w, hB_.x, hB_.y, hB_.z, hB_.w};
            #pragma unroll
            for (int b = 0; b < NB; ++b) {
                acc[0][b] = fmaf(hb[b], c0, acc[0][b]);
                acc[1][b] = fmaf(hb[b], c1, acc[1][b]);
                acc[2][b] = fmaf(hb[b], c2, acc[2][b]);
                acc[3][b] = fmaf(hb[b], vv, acc[3][b]);
            }
        }
        __syncthreads();                 // readers of buf[bi] done (R0n aged by compute)
        if (s < 31) {
            buf[bi ^ 1][d0] = R0;        // write stage s+1
            buf[bi ^ 1][d1] = R1;
            R0 = R0n; R1 = R1n;
            __syncthreads();             // buf[bi^1] visible for stage s+1
        }
    }
    __syncthreads();                     // all compute done before part[] overlay

    // cross-slice reduce (r4's proven two-phase) + epilogue
    const int bp = ks;
    const int v  = blk * 64 + p;
    const float factor = 0.5f * DD;
    float* pp = part + (ks * 64 + p) * PSTR;

    #pragma unroll
    for (int phase = 0; phase < 2; ++phase) {
        if (phase) __syncthreads();
        #pragma unroll
        for (int q = 0; q < 4; ++q) {
            int b = phase * 4 + q;
            pp[q * 4 + 0] = acc[0][b]; pp[q * 4 + 1] = acc[1][b];
            pp[q * 4 + 2] = acc[2][b]; pp[q * 4 + 3] = acc[3][b];
        }
        __syncthreads();
        {
            const int b = phase * 4 + bp;
            float A0 = 0.f, A1 = 0.f, A2 = 0.f, A3 = 0.f;
            #pragma unroll
            for (int k2 = 0; k2 < 4; ++k2) {
                const float* rp = part + (k2 * 64 + p) * PSTR + bp * 4;
                A0 += rp[0]; A1 += rp[1]; A2 += rp[2]; A3 += rp[3];
            }
            float px = factor * (coords0[3 * v]     + (A0 + bc[3 * v]))     + factor;
            float py = factor * (coords0[3 * v + 1] + (A1 + bc[3 * v + 1])) + factor;
            float pz = factor * (coords0[3 * v + 2] + (A2 + bc[3 * v + 2])) + factor;
            float val = fmaxf(values0[v] + (A3 + bv[v]), 0.f);
            posval[(size_t)b * NV + v] = make_float4(px, py, pz, val);
        }
    }
}

// ----------------------------- binning helpers -------------------------------------
__device__ __forceinline__ bool point_base(float4 q, int& ix, int& iy, int& iz) {
    if (q.w == 0.f) return false;
    ix = (int)floorf(q.x); iy = (int)floorf(q.y); iz = (int)floorf(q.z);
    return ix >= -1 && ix <= 127 && iy >= -1 && iy <= 127 && iz >= -1 && iz <= 127;
}

__device__ __forceinline__ void brick_span(int ix, int iy, int iz,
                                           int& bx0, int& bx1, int& by0, int& by1,
                                           int& bz0, int& bz1) {
    bx0 = (ix < 0 ? 0 : ix) >> 5;  bx1 = (ix + 1 > 127 ? 127 : ix + 1) >> 5;
    by0 = (iy < 0 ? 0 : iy) >> 3;  by1 = (iy + 1 > 127 ? 127 : iy + 1) >> 3;
    bz0 = (iz < 0 ? 0 : iz) >> 2;  bz1 = (iz + 1 > 127 ? 127 : iz + 1) >> 2;
}

// --------------- k_count: LDS histogram of (duplicated) entries per brick ----------
__global__ __launch_bounds__(256) void k_count(const float4* __restrict__ posval,
                                               unsigned* __restrict__ binCount)
{
    __shared__ unsigned hist[NBIN];
    const int tid = threadIdx.x;
    const int batch = blockIdx.x >> 5;
    const size_t base = (size_t)batch * NV + (blockIdx.x & 31) * 2048;
    for (int i = tid; i < NBIN; i += 256) hist[i] = 0;
    __syncthreads();
    #pragma unroll
    for (int j = 0; j < 8; ++j) {
        float4 q = posval[base + j * 256 + tid];
        int ix, iy, iz;
        if (point_base(q, ix, iy, iz)) {
            int bx0, bx1, by0, by1, bz0, bz1;
            brick_span(ix, iy, iz, bx0, bx1, by0, by1, bz0, bz1);
            for (int bz = bz0; bz <= bz1; ++bz)
                for (int by = by0; by <= by1; ++by)
                    for (int bx = bx0; bx <= bx1; ++bx)
                        atomicAdd(&hist[(bz * 16 + by) * 4 + bx], 1u);
        }
    }
    __syncthreads();
    for (int i = tid; i < NBIN; i += 256) {
        unsigned c = hist[i];
        if (c) atomicAdd(&binCount[batch * NBIN + i], c);
    }
}

// --------------- k_scan: exclusive scan over 16384 bins (single block) -------------
__global__ __launch_bounds__(1024) void k_scan(const unsigned* __restrict__ cnt,
                                               unsigned* __restrict__ start,
                                               unsigned* __restrict__ cursor)
{
    __shared__ unsigned partial[1024];
    const int t = threadIdx.x;
    const int base = t * 16;
    unsigned s = 0;
    #pragma unroll
    for (int j = 0; j < 16; ++j) s += cnt[base + j];
    partial[t] = s;
    __syncthreads();
    for (int off = 1; off < 1024; off <<= 1) {
        unsigned mine = partial[t];
        unsigned add = (t >= off) ? partial[t - off] : 0u;
        __syncthreads();
        partial[t] = mine + add;
        __syncthreads();
    }
    unsigned run = (t > 0) ? partial[t - 1] : 0u;
    #pragma unroll
    for (int j = 0; j < 16; ++j) {
        start[base + j] = run;
        cursor[base + j] = run;
        run += cnt[base + j];
    }
    if (t == 1023) start[NBIN_TOT] = partial[1023];
}

// -------- k_scatter: copy each point into every touched brick's contiguous range ----
__global__ __launch_bounds__(256) void k_scatter(const float4* __restrict__ posval,
                                                 unsigned* __restrict__ binCursor,
                                                 float4* __restrict__ sorted)
{
    __shared__ unsigned hist[NBIN];
    __shared__ unsigned bbase[NBIN];
    const int tid = threadIdx.x;
    const int batch = blockIdx.x >> 5;
    const size_t base = (size_t)batch * NV + (blockIdx.x & 31) * 2048;
    for (int i = tid; i < NBIN; i += 256) hist[i] = 0;
    __syncthreads();

    float4 q[8];
    #pragma unroll
    for (int j = 0; j < 8; ++j) {
        q[j] = posval[base + j * 256 + tid];
        int ix, iy, iz;
        if (point_base(q[j], ix, iy, iz)) {
            int bx0, bx1, by0, by1, bz0, bz1;
            brick_span(ix, iy, iz, bx0, bx1, by0, by1, bz0, bz1);
            for (int bz = bz0; bz <= bz1; ++bz)
                for (int by = by0; by <= by1; ++by)
                    for (int bx = bx0; bx <= bx1; ++bx)
                        atomicAdd(&hist[(bz * 16 + by) * 4 + bx], 1u);
        }
    }
    __syncthreads();
    for (int i = tid; i < NBIN; i += 256) {
        unsigned c = hist[i];
        bbase[i] = c ? atomicAdd(&binCursor[batch * NBIN + i], c) : 0u;
    }
    __syncthreads();
    for (int i = tid; i < NBIN; i += 256) hist[i] = 0;
    __syncthreads();
    #pragma unroll
    for (int j = 0; j < 8; ++j) {
        int ix, iy, iz;
        if (point_base(q[j], ix, iy, iz)) {
            int bx0, bx1, by0, by1, bz0, bz1;
            brick_span(ix, iy, iz, bx0, bx1, by0, by1, bz0, bz1);
            for (int bz = bz0; bz <= bz1; ++bz)
                for (int by = by0; by <= by1; ++by)
                    for (int bx = bx0; bx <= bx1; ++bx) {
                        int bin = (bz * 16 + by) * 4 + bx;
                        unsigned r = atomicAdd(&hist[bin], 1u);
                        sorted[bbase[bin] + r] = q[j];
                    }
        }
    }
}

// -------- k_binsplat: one block per 32x8x4 brick; exact list; LDS accumulate -------
__global__ __launch_bounds__(256) void k_binsplat(const float4* __restrict__ sorted,
                                                  const unsigned* __restrict__ binStart,
                                                  float* __restrict__ grid)
{
    __shared__ float brick[4 * 8 * 32];
    const int tid = threadIdx.x;
    const int bid = blockIdx.x;
    const int bx = bid & 3;
    const int by = (bid >> 2) & 15;
    const int bz = (bid >> 6) & 31;
    const int batch = bid >> 11;
    const int x0 = bx << 5, y0 = by << 3, z0 = bz << 2;

    const unsigned s = binStart[bid], e = binStart[bid + 1];

    const int vx4 = tid & 7, cy = (tid >> 3) & 7, cz = tid >> 6;
    const size_t o = (size_t)batch * D3 + (size_t)(z0 + cz) * (DD * DD)
                   + (size_t)(y0 + cy) * DD + x0 + vx4 * 4;

    if (s == e) {
        *reinterpret_cast<float4*>(grid + o) = make_float4(0.f, 0.f, 0.f, 0.f);
        return;
    }

    for (int i = tid; i < 1024; i += 256) brick[i] = 0.f;
    __syncthreads();

    for (unsigned i = s + tid; i < e; i += 256) {
        float4 q = sorted[i];
        float fx = floorf(q.x), fy = floorf(q.y), fz = floorf(q.z);
        int vx = (int)fx - x0, vy = (int)fy - y0, vz = (int)fz - z0;
        float gx = q.x - fx, gy = q.y - fy, gz = q.z - fz;
        float wx0 = 1.f - gx, wy0 = 1.f - gy, wz0 = 1.f - gz;
        #pragma unroll
        for (int oz = 0; oz < 2; ++oz)
        #pragma unroll
        for (int oy = 0; oy < 2; ++oy)
        #pragma unroll
        for (int ox = 0; ox < 2; ++ox) {
            int cxx = vx + ox, cyy = vy + oy, czz = vz + oz;
            if ((unsigned)cxx < 32u && (unsigned)cyy < 8u && (unsigned)czz < 4u) {
                float w = ((ox ? gx : wx0) * (oy ? gy : wy0)) * (oz ? gz : wz0);
                atomicAdd(&brick[(czz * 8 + cyy) * 32 + cxx], q.w * w);
            }
        }
    }
    __syncthreads();

    *reinterpret_cast<float4*>(grid + o) =
        *reinterpret_cast<const float4*>(&brick[(cz * 8 + cy) * 32 + vx4 * 4]);
}

// ------------------------- separable 7-tap gaussian blur (pencil) ------------------
__global__ __launch_bounds__(256) void k_blur(const float* __restrict__ in,
                                              float* __restrict__ out, int shift)
{
    const long i = (long)blockIdx.x * 256 + threadIdx.x;
    const int p = (int)((i >> shift) & (DD - 1));

    const double e1 = 0.6065306597126334, e2 = 0.1353352832366127, e3 = 0.011108996538242306;
    const double s = 1.0 + 2.0 * (e1 + e2 + e3);
    const float kw[7] = {(float)(e3 / s), (float)(e2 / s), (float)(e1 / s), (float)(1.0 / s),
                         (float)(e1 / s), (float)(e2 / s), (float)(e3 / s)};

    float acc = 0.f;
    #pragma unroll
    for (int j = -3; j <= 3; ++j) {
        int q = p + j;
        if (q >= 0 && q < DD)
            acc = fmaf(kw[j + 3], in[i + ((long)j << shift)], acc);
    }
    out[i] = acc;
}

// ------------------ fused y+x blur: 32-row y-strips per (batch, z) -----------------
__global__ __launch_bounds__(256) void k_blur_yx(const float* __restrict__ in,
                                                 float* __restrict__ out)
{
    __shared__ float sin_[38 * 128];
    __shared__ float sy[32 * 128];

    const double e1 = 0.6065306597126334, e2 = 0.1353352832366127, e3 = 0.011108996538242306;
    const double ss = 1.0 + 2.0 * (e1 + e2 + e3);
    const float kw[7] = {(float)(e3 / ss), (float)(e2 / ss), (float)(e1 / ss), (float)(1.0 / ss),
                         (float)(e1 / ss), (float)(e2 / ss), (float)(e3 / ss)};

    const int tid = threadIdx.x;
    const int bid = blockIdx.x;
    const int ytile = bid & 3;
    const int z = (bid >> 2) & 127;
    const int batch = bid >> 9;
    const int y0 = ytile << 5;
    const size_t slab = (size_t)batch * D3 + (size_t)z * (DD * DD);

    for (int i = tid; i < 38 * 128; i += 256) {
        int row = i >> 7, xx = i & 127;
        int gy = y0 + row - 3;
        sin_[i] = (gy >= 0 && gy < DD) ? in[slab + (size_t)gy * DD + xx] : 0.f;
    }
    __syncthreads();

    for (int i = tid; i < 32 * 128; i += 256) {
        int r = i >> 7, xx = i & 127;
        float acc = 0.f;
        #pragma unroll
        for (int j = 0; j < 7; ++j)
            acc = fmaf(kw[j], sin_[(r + j) * 128 + xx], acc);
        sy[i] = acc;
    }
    __syncthreads();

    for (int i = tid; i < 32 * 128; i += 256) {
        int r = i >> 7, xx = i & 127;
        float acc = 0.f;
        #pragma unroll
        for (int j = -3; j <= 3; ++j) {
            int qx = xx + j;
            if (qx >= 0 && qx < DD)
                acc = fmaf(kw[j + 3], sy[r * 128 + qx], acc);
        }
        out[slab + (size_t)(y0 + r) * DD + xx] = acc;
    }
}

extern "C" void kernel_launch(void* const* d_in, const int* in_sizes, int n_in,
                              void* d_out, int out_size, void* d_ws, size_t ws_size,
                              hipStream_t stream) {
    const float* x   = (const float*)d_in[0];
    const float* w0  = (const float*)d_in[1];
    const float* b0  = (const float*)d_in[2];
    const float* w1  = (const float*)d_in[3];
    const float* b1  = (const float*)d_in[4];
    const float* w2  = (const float*)d_in[5];
    const float* b2  = (const float*)d_in[6];
    const float* w3  = (const float*)d_in[7];
    const float* b3  = (const float*)d_in[8];
    const float* w4  = (const float*)d_in[9];
    const float* b4  = (const float*)d_in[10];
    const float* wc  = (const float*)d_in[11];
    const float* bc  = (const float*)d_in[12];
    const float* wv  = (const float*)d_in[13];
    const float* bv  = (const float*)d_in[14];
    const float* c0  = (const float*)d_in[15];
    const float* v0  = (const float*)d_in[16];

    float* out = (float*)d_out;
    // d_out staging (consumed before k_binsplat rewrites d_out as the raw grid):
    float4* posval = (float4*)d_out;                  // [NB][NV] float4 = 8 MiB
    float* h4 = out + 4 * 1024 * 1024;                // at +16 MiB
    float* hA = h4 + 2048;
    float* hB = hA + 2048;
    // ws staging (consumed before blur-z rewrites ws with the 64MB grid):
    float4* sorted = (float4*)d_ws;
    unsigned* binCount  = (unsigned*)((char*)d_ws + (48u << 20));
    unsigned* binStart  = binCount + NBIN_TOT;
    unsigned* binCursor = binStart + NBIN_TOT + 1;

    hipMemsetAsync(binCount, 0, NBIN_TOT * sizeof(unsigned), stream);

    // SIREN MLP: 5 per-layer kernels, 4 blocks each (proven r6 chain)
    k_layer<LAT, 0><<<4, 256, 0, stream>>>(x,  w0, b0, hA);
    k_layer<HID, 1><<<4, 256, 0, stream>>>(hA, w1, b1, hB);
    k_layer<HID, 1><<<4, 256, 0, stream>>>(hB, w2, b2, hA);
    k_layer<HID, 1><<<4, 256, 0, stream>>>(hA, w3, b3, hB);
    k_layer<HID, 2><<<4, 256, 0, stream>>>(hB, w4, b4, h4);

    k_heads<<<NV / 64, 256, 0, stream>>>(h4, wc, bc, wv, bv, c0, v0, posval);

    k_count<<<256, 256, 0, stream>>>(posval, binCount);
    k_scan<<<1, 1024, 0, stream>>>(binCount, binStart, binCursor);
    k_scatter<<<256, 256, 0, stream>>>(posval, binCursor, sorted);
    k_binsplat<<<NBIN_TOT, 256, 0, stream>>>(sorted, binStart, out);

    const int nblk = (NB * D3) / 256;
    k_blur<<<nblk, 256, 0, stream>>>(out, (float*)d_ws, 14);
    k_blur_yx<<<NB * 512, 256, 0, stream>>>((float*)d_ws, out);
}

// Round 13
// 306.267 us; speedup vs baseline: 1.3090x; 1.1616x over previous
//
#include <hip/hip_runtime.h>
#include <hip/hip_bf16.h>

#define DD 128
#define D3 (DD*DD*DD)      // 2097152
#define NB 8               // batch
#define NV 65536           // points
#define HID 256
#define LAT 128

// bricks: 32x8x4 voxels -> 2048 per batch, 16384 total
#define NBIN 2048
#define NBIN_TOT (NBIN*NB)
#define NMASK 512          // [batch][zc 0..7][yc 0..7], 16-voxel cells in y,z

// round-to-nearest-even f32 -> bf16, returned as the (exactly representable) f32 value
__device__ __forceinline__ float rbf(float x) {
    unsigned u = __float_as_uint(x);
    unsigned r = (u + 0x7fffu + ((u >> 16) & 1u)) & 0xFFFF0000u;
    return __uint_as_float(r);
}

// ---------------- SIREN layer: one kernel per layer, 4 blocks x 256 threads --------
template<int K, int MODE>
__global__ __launch_bounds__(256) void k_layer(
    const float* __restrict__ in, const float* __restrict__ w,
    const float* __restrict__ bias, float* __restrict__ outp)
{
    __shared__ float in_s[NB * K];
    __shared__ float part[4 * 64 * 8];
    const int tid = threadIdx.x;
    for (int i = tid; i < NB * K; i += 256) in_s[i] = rbf(in[i]);
    __syncthreads();

    const int cl = tid & 63;
    const int ks = tid >> 6;
    const int col = blockIdx.x * 64 + cl;

    float acc[NB];
    #pragma unroll
    for (int b = 0; b < NB; ++b) acc[b] = 0.f;

    const int k0 = ks * (K / 4);
    #pragma unroll 8
    for (int k = k0; k < k0 + K / 4; ++k) {
        float wk = rbf(w[k * HID + col]);
        #pragma unroll
        for (int b = 0; b < NB; ++b) acc[b] = fmaf(in_s[b * K + k], wk, acc[b]);
    }

    float* pp = part + (ks * 64 + cl) * 8;
    #pragma unroll
    for (int b = 0; b < NB; ++b) pp[b] = acc[b];
    __syncthreads();

    #pragma unroll
    for (int u = 0; u < 2; ++u) {
        const int idx = tid * 2 + u;
        const int c2 = idx >> 3, b = idx & 7;
        const int gcol = blockIdx.x * 64 + c2;
        float s = (part[(0 * 64 + c2) * 8 + b] + part[(1 * 64 + c2) * 8 + b])
                + (part[(2 * 64 + c2) * 8 + b] + part[(3 * 64 + c2) * 8 + b]);
        float t = rbf(s);
        t = rbf(t + rbf(bias[gcol]));
        if (MODE == 0) {
            t = rbf(30.0f * t);
            t = rbf(sinf(t));
        } else if (MODE == 1) {
            float r = rbf(in_s[b * K + gcol] + t);
            t = rbf(sinf(r));
        }
        outp[b * HID + gcol] = t;
    }
}

// ------ heads: staged streaming GEMV (r12 verbatim: ties best total) ---------------
#define PSTR 17
__global__ __launch_bounds__(256, 4) void k_heads(
    const float* __restrict__ h4,
    const float* __restrict__ wc, const float* __restrict__ bc,
    const float* __restrict__ wv, const float* __restrict__ bv,
    const float* __restrict__ coords0, const float* __restrict__ values0,
    float4* __restrict__ posval)
{
    __shared__ float hsT[HID * NB];
    __shared__ __align__(16) char uni[4 * 64 * PSTR * 4];
    float4 (*buf)[512] = reinterpret_cast<float4(*)[512]>(uni);
    float* part = reinterpret_cast<float*>(uni);

    const int tid = threadIdx.x;
    const int blk = blockIdx.x;
    const int p   = tid & 63;
    const int ks  = tid >> 6;

    for (int i = tid; i < NB * HID; i += 256) {
        int b = i >> 8, k = i & 255;
        hsT[k * 8 + b] = h4[b * HID + k];
    }

    const float4* wc4 = reinterpret_cast<const float4*>(wc);
    const float4* wv4 = reinterpret_cast<const float4*>(wv);

    size_t base0, base1, step1;
    {
        int r = tid / 48, c = tid - r * 48;
        base0 = (size_t)((r >> 1) * 64 + (r & 1)) * 49152 + (size_t)blk * 48 + c;
    }
    const float4* src1;
    if (tid < 128) {
        int t1 = tid + 256;
        int r = t1 / 48, c = t1 - r * 48;
        base1 = (size_t)((r >> 1) * 64 + (r & 1)) * 49152 + (size_t)blk * 48 + c;
        src1 = wc4; step1 = 2 * 49152;
    } else {
        int u = tid - 128;
        int r = u >> 4, c = u & 15;
        base1 = (size_t)((r >> 1) * 64 + (r & 1)) * 16384 + (size_t)blk * 16 + c;
        src1 = wv4; step1 = 2 * 16384;
    }
    const size_t step0 = 2 * 49152;
    const int d0 = tid, d1 = tid + 256;

    float acc[4][8];
    #pragma unroll
    for (int c = 0; c < 4; ++c)
        #pragma unroll
        for (int b = 0; b < NB; ++b) acc[c][b] = 0.f;

    const float4* h4v = reinterpret_cast<const float4*>(hsT);

    float4 R0 = wc4[base0];
    float4 R1 = src1[base1];
    buf[0][d0] = R0; buf[0][d1] = R1;
    R0 = wc4[base0 + step0];
    R1 = src1[base1 + step1];
    __syncthreads();

    float4 R0n, R1n;
    for (int s = 0; s < 32; ++s) {
        if (s + 2 < 32) {
            R0n = wc4[base0 + (size_t)(s + 2) * step0];
            R1n = src1[base1 + (size_t)(s + 2) * step1];
        }
        const int bi = s & 1;
        const float* wcsF = reinterpret_cast<const float*>(&buf[bi][0]);
        const float* wvsF = reinterpret_cast<const float*>(&buf[bi][384]);
        #pragma unroll
        for (int j = 0; j < 2; ++j) {
            const int r = ks * 2 + j;
            const int k = ks * 64 + 2 * s + j;
            float c0 = wcsF[r * 192 + 3 * p];
            float c1 = wcsF[r * 192 + 3 * p + 1];
            float c2 = wcsF[r * 192 + 3 * p + 2];
            float vv = wvsF[r * 64 + p];
            float4 hA_ = h4v[k * 2], hB_ = h4v[k * 2 + 1];
            float hb[8] = {hA_.x, hA_.y, hA_.z, hA_.w, hB_.x, hB_.y, hB_.z, hB_.w};
            #pragma unroll
            for (int b = 0; b < NB; ++b) {
                acc[0][b] = fmaf(hb[b], c0, acc[0][b]);
                acc[1][b] = fmaf(hb[b], c1, acc[1][b]);
                acc[2][b] = fmaf(hb[b], c2, acc[2][b]);
                acc[3][b] = fmaf(hb[b], vv, acc[3][b]);
            }
        }
        __syncthreads();
        if (s < 31) {
            buf[bi ^ 1][d0] = R0;
            buf[bi ^ 1][d1] = R1;
            R0 = R0n; R1 = R1n;
            __syncthreads();
        }
    }
    __syncthreads();

    const int bp = ks;
    const int v  = blk * 64 + p;
    const float factor = 0.5f * DD;
    float* pp = part + (ks * 64 + p) * PSTR;

    #pragma unroll
    for (int phase = 0; phase < 2; ++phase) {
        if (phase) __syncthreads();
        #pragma unroll
        for (int q = 0; q < 4; ++q) {
            int b = phase * 4 + q;
            pp[q * 4 + 0] = acc[0][b]; pp[q * 4 + 1] = acc[1][b];
            pp[q * 4 + 2] = acc[2][b]; pp[q * 4 + 3] = acc[3][b];
        }
        __syncthreads();
        {
            const int b = phase * 4 + bp;
            float A0 = 0.f, A1 = 0.f, A2 = 0.f, A3 = 0.f;
            #pragma unroll
            for (int k2 = 0; k2 < 4; ++k2) {
                const float* rp = part + (k2 * 64 + p) * PSTR + bp * 4;
                A0 += rp[0]; A1 += rp[1]; A2 += rp[2]; A3 += rp[3];
            }
            float px = factor * (coords0[3 * v]     + (A0 + bc[3 * v]))     + factor;
            float py = factor * (coords0[3 * v + 1] + (A1 + bc[3 * v + 1])) + factor;
            float pz = factor * (coords0[3 * v + 2] + (A2 + bc[3 * v + 2])) + factor;
            float val = fmaxf(values0[v] + (A3 + bv[v]), 0.f);
            posval[(size_t)b * NV + v] = make_float4(px, py, pz, val);
        }
    }
}

// ----------------------------- binning helpers -------------------------------------
__device__ __forceinline__ bool point_base(float4 q, int& ix, int& iy, int& iz) {
    if (q.w == 0.f) return false;
    ix = (int)floorf(q.x); iy = (int)floorf(q.y); iz = (int)floorf(q.z);
    return ix >= -1 && ix <= 127 && iy >= -1 && iy <= 127 && iz >= -1 && iz <= 127;
}

__device__ __forceinline__ void brick_span(int ix, int iy, int iz,
                                           int& bx0, int& bx1, int& by0, int& by1,
                                           int& bz0, int& bz1) {
    bx0 = (ix < 0 ? 0 : ix) >> 5;  bx1 = (ix + 1 > 127 ? 127 : ix + 1) >> 5;
    by0 = (iy < 0 ? 0 : iy) >> 3;  by1 = (iy + 1 > 127 ? 127 : iy + 1) >> 3;
    bz0 = (iz < 0 ? 0 : iz) >> 2;  bz1 = (iz + 1 > 127 ? 127 : iz + 1) >> 2;
}

// --------------- k_count: brick histogram + (y,z) influence mask ------------------
// mask cell (b, zc, yc) marked iff some point's influence box [i-3, i+4] touches it.
// box = splat support (+1) dilated by the two blur passes (±3): superset of every
// nonzero voxel in raw grid, z-blurred grid, and final output.
__global__ __launch_bounds__(256) void k_count(const float4* __restrict__ posval,
                                               unsigned* __restrict__ binCount,
                                               unsigned* __restrict__ gmask)
{
    __shared__ unsigned hist[NBIN];
    __shared__ unsigned lmask[64];
    const int tid = threadIdx.x;
    const int batch = blockIdx.x >> 5;
    const size_t base = (size_t)batch * NV + (blockIdx.x & 31) * 2048;
    for (int i = tid; i < NBIN; i += 256) hist[i] = 0;
    if (tid < 64) lmask[tid] = 0;
    __syncthreads();
    #pragma unroll
    for (int j = 0; j < 8; ++j) {
        float4 q = posval[base + j * 256 + tid];
        int ix, iy, iz;
        if (point_base(q, ix, iy, iz)) {
            int bx0, bx1, by0, by1, bz0, bz1;
            brick_span(ix, iy, iz, bx0, bx1, by0, by1, bz0, bz1);
            for (int bz = bz0; bz <= bz1; ++bz)
                for (int by = by0; by <= by1; ++by)
                    for (int bx = bx0; bx <= bx1; ++bx)
                        atomicAdd(&hist[(bz * 16 + by) * 4 + bx], 1u);
            int ylo = iy - 3 < 0 ? 0 : iy - 3, yhi = iy + 4 > 127 ? 127 : iy + 4;
            int zlo = iz - 3 < 0 ? 0 : iz - 3, zhi = iz + 4 > 127 ? 127 : iz + 4;
            for (int zc = zlo >> 4; zc <= zhi >> 4; ++zc)
                for (int yc = ylo >> 4; yc <= yhi >> 4; ++yc)
                    lmask[zc * 8 + yc] = 1u;   // idempotent racy write of 1: fine
        }
    }
    __syncthreads();
    for (int i = tid; i < NBIN; i += 256) {
        unsigned c = hist[i];
        if (c) atomicAdd(&binCount[batch * NBIN + i], c);
    }
    if (tid < 64 && lmask[tid]) atomicOr(&gmask[batch * 64 + tid], 1u);
}

// --------------- k_scan: exclusive scan over 16384 bins (single block) -------------
__global__ __launch_bounds__(1024) void k_scan(const unsigned* __restrict__ cnt,
                                               unsigned* __restrict__ start,
                                               unsigned* __restrict__ cursor)
{
    __shared__ unsigned partial[1024];
    const int t = threadIdx.x;
    const int base = t * 16;
    unsigned s = 0;
    #pragma unroll
    for (int j = 0; j < 16; ++j) s += cnt[base + j];
    partial[t] = s;
    __syncthreads();
    for (int off = 1; off < 1024; off <<= 1) {
        unsigned mine = partial[t];
        unsigned add = (t >= off) ? partial[t - off] : 0u;
        __syncthreads();
        partial[t] = mine + add;
        __syncthreads();
    }
    unsigned run = (t > 0) ? partial[t - 1] : 0u;
    #pragma unroll
    for (int j = 0; j < 16; ++j) {
        start[base + j] = run;
        cursor[base + j] = run;
        run += cnt[base + j];
    }
    if (t == 1023) start[NBIN_TOT] = partial[1023];
}

// -------- k_scatter: copy each point into every touched brick's contiguous range ----
__global__ __launch_bounds__(256) void k_scatter(const float4* __restrict__ posval,
                                                 unsigned* __restrict__ binCursor,
                                                 float4* __restrict__ sorted)
{
    __shared__ unsigned hist[NBIN];
    __shared__ unsigned bbase[NBIN];
    const int tid = threadIdx.x;
    const int batch = blockIdx.x >> 5;
    const size_t base = (size_t)batch * NV + (blockIdx.x & 31) * 2048;
    for (int i = tid; i < NBIN; i += 256) hist[i] = 0;
    __syncthreads();

    float4 q[8];
    #pragma unroll
    for (int j = 0; j < 8; ++j) {
        q[j] = posval[base + j * 256 + tid];
        int ix, iy, iz;
        if (point_base(q[j], ix, iy, iz)) {
            int bx0, bx1, by0, by1, bz0, bz1;
            brick_span(ix, iy, iz, bx0, bx1, by0, by1, bz0, bz1);
            for (int bz = bz0; bz <= bz1; ++bz)
                for (int by = by0; by <= by1; ++by)
                    for (int bx = bx0; bx <= bx1; ++bx)
                        atomicAdd(&hist[(bz * 16 + by) * 4 + bx], 1u);
        }
    }
    __syncthreads();
    for (int i = tid; i < NBIN; i += 256) {
        unsigned c = hist[i];
        bbase[i] = c ? atomicAdd(&binCursor[batch * NBIN + i], c) : 0u;
    }
    __syncthreads();
    for (int i = tid; i < NBIN; i += 256) hist[i] = 0;
    __syncthreads();
    #pragma unroll
    for (int j = 0; j < 8; ++j) {
        int ix, iy, iz;
        if (point_base(q[j], ix, iy, iz)) {
            int bx0, bx1, by0, by1, bz0, bz1;
            brick_span(ix, iy, iz, bx0, bx1, by0, by1, bz0, bz1);
            for (int bz = bz0; bz <= bz1; ++bz)
                for (int by = by0; by <= by1; ++by)
                    for (int bx = bx0; bx <= bx1; ++bx) {
                        int bin = (bz * 16 + by) * 4 + bx;
                        unsigned r = atomicAdd(&hist[bin], 1u);
                        sorted[bbase[bin] + r] = q[j];
                    }
        }
    }
}

// -------- k_binsplat: one block per 32x8x4 brick; mask-gated; LDS accumulate -------
__global__ __launch_bounds__(256) void k_binsplat(const float4* __restrict__ sorted,
                                                  const unsigned* __restrict__ binStart,
                                                  const unsigned* __restrict__ gmask,
                                                  int maskon,
                                                  float* __restrict__ grid)
{
    __shared__ float brick[4 * 8 * 32];
    const int tid = threadIdx.x;
    const int bid = blockIdx.x;
    const int bx = bid & 3;
    const int by = (bid >> 2) & 15;
    const int bz = (bid >> 6) & 31;
    const int batch = bid >> 11;
    const int x0 = bx << 5, y0 = by << 3, z0 = bz << 2;

    // unmarked cell => provably empty brick AND never read by masked blur-z
    if (maskon && gmask[batch * 64 + (bz >> 2) * 8 + (by >> 1)] == 0u) return;

    const unsigned s = binStart[bid], e = binStart[bid + 1];

    const int vx4 = tid & 7, cy = (tid >> 3) & 7, cz = tid >> 6;
    const size_t o = (size_t)batch * D3 + (size_t)(z0 + cz) * (DD * DD)
                   + (size_t)(y0 + cy) * DD + x0 + vx4 * 4;

    if (s == e) {
        *reinterpret_cast<float4*>(grid + o) = make_float4(0.f, 0.f, 0.f, 0.f);
        return;
    }

    for (int i = tid; i < 1024; i += 256) brick[i] = 0.f;
    __syncthreads();

    for (unsigned i = s + tid; i < e; i += 256) {
        float4 q = sorted[i];
        float fx = floorf(q.x), fy = floorf(q.y), fz = floorf(q.z);
        int vx = (int)fx - x0, vy = (int)fy - y0, vz = (int)fz - z0;
        float gx = q.x - fx, gy = q.y - fy, gz = q.z - fz;
        float wx0 = 1.f - gx, wy0 = 1.f - gy, wz0 = 1.f - gz;
        #pragma unroll
        for (int oz = 0; oz < 2; ++oz)
        #pragma unroll
        for (int oy = 0; oy < 2; ++oy)
        #pragma unroll
        for (int ox = 0; ox < 2; ++ox) {
            int cxx = vx + ox, cyy = vy + oy, czz = vz + oz;
            if ((unsigned)cxx < 32u && (unsigned)cyy < 8u && (unsigned)czz < 4u) {
                float w = ((ox ? gx : wx0) * (oy ? gy : wy0)) * (oz ? gz : wz0);
                atomicAdd(&brick[(czz * 8 + cyy) * 32 + cxx], q.w * w);
            }
        }
    }
    __syncthreads();

    *reinterpret_cast<float4*>(grid + o) =
        *reinterpret_cast<const float4*>(&brick[(cz * 8 + cy) * 32 + vx4 * 4]);
}

// ---------------- z blur, mask-gated: skip unmarked blocks entirely ----------------
__global__ __launch_bounds__(256) void k_blur_z(const float* __restrict__ in,
                                                float* __restrict__ out,
                                                const unsigned* __restrict__ gmask,
                                                int maskon)
{
    const int b = blockIdx.x;
    const int batch = b >> 13;
    const int z = (b >> 6) & 127;
    const int y0 = (b * 2) & 127;           // block covers rows y0, y0+1 (same yc)
    const long i = (long)b * 256 + threadIdx.x;

    unsigned okbits = 0x7fu;
    if (maskon) {
        if (gmask[batch * 64 + (z >> 4) * 8 + (y0 >> 4)] == 0u) return;  // no write
        okbits = 0u;
        #pragma unroll
        for (int j = -3; j <= 3; ++j) {
            int zj = z + j;
            if (zj >= 0 && zj < DD && gmask[batch * 64 + (zj >> 4) * 8 + (y0 >> 4)])
                okbits |= 1u << (j + 3);
        }
    }

    const double e1 = 0.6065306597126334, e2 = 0.1353352832366127, e3 = 0.011108996538242306;
    const double s = 1.0 + 2.0 * (e1 + e2 + e3);
    const float kw[7] = {(float)(e3 / s), (float)(e2 / s), (float)(e1 / s), (float)(1.0 / s),
                         (float)(e1 / s), (float)(e2 / s), (float)(e3 / s)};

    float acc = 0.f;
    #pragma unroll
    for (int j = -3; j <= 3; ++j) {
        int q = z + j;
        if (q >= 0 && q < DD && ((okbits >> (j + 3)) & 1u))
            acc = fmaf(kw[j + 3], in[i + ((long)j << 14)], acc);
    }
    out[i] = acc;
}

// ------------- fused y+x blur, mask-gated zero-fast-path + halo substitution -------
__global__ __launch_bounds__(256) void k_blur_yx(const float* __restrict__ in,
                                                 float* __restrict__ out,
                                                 const unsigned* __restrict__ gmask,
                                                 int maskon)
{
    __shared__ float sin_[38 * 128];
    __shared__ float sy[32 * 128];
    __shared__ unsigned mrow[8];

    const double e1 = 0.6065306597126334, e2 = 0.1353352832366127, e3 = 0.011108996538242306;
    const double ss = 1.0 + 2.0 * (e1 + e2 + e3);
    const float kw[7] = {(float)(e3 / ss), (float)(e2 / ss), (float)(e1 / ss), (float)(1.0 / ss),
                         (float)(e1 / ss), (float)(e2 / ss), (float)(e3 / ss)};

    const int tid = threadIdx.x;
    const int bid = blockIdx.x;
    const int ytile = bid & 3;
    const int z = (bid >> 2) & 127;
    const int batch = bid >> 9;
    const int y0 = ytile << 5;
    const size_t slab = (size_t)batch * D3 + (size_t)z * (DD * DD);

    if (maskon) {
        if (tid < 8) mrow[tid] = gmask[batch * 64 + (z >> 4) * 8 + tid];
        __syncthreads();
        const int yc0 = y0 >> 4;
        if (mrow[yc0] == 0u && mrow[yc0 + 1] == 0u) {
            // outputs provably zero: coalesced zero-write, no reads
            const float4 z4 = make_float4(0.f, 0.f, 0.f, 0.f);
            for (int i = tid; i < 1024; i += 256) {
                int r = i >> 5, xq = i & 31;
                *reinterpret_cast<float4*>(&out[slab + (size_t)(y0 + r) * DD + xq * 4]) = z4;
            }
            return;
        }
    }

    for (int i = tid; i < 38 * 128; i += 256) {
        int row = i >> 7, xx = i & 127;
        int gy = y0 + row - 3;
        bool ok = gy >= 0 && gy < DD && (!maskon || mrow[gy >> 4]);
        sin_[i] = ok ? in[slab + (size_t)gy * DD + xx] : 0.f;   // unmarked ws rows: true 0
    }
    __syncthreads();

    for (int i = tid; i < 32 * 128; i += 256) {
        int r = i >> 7, xx = i & 127;
        float acc = 0.f;
        #pragma unroll
        for (int j = 0; j < 7; ++j)
            acc = fmaf(kw[j], sin_[(r + j) * 128 + xx], acc);
        sy[i] = acc;
    }
    __syncthreads();

    for (int i = tid; i < 32 * 128; i += 256) {
        int r = i >> 7, xx = i & 127;
        float acc = 0.f;
        #pragma unroll
        for (int j = -3; j <= 3; ++j) {
            int qx = xx + j;
            if (qx >= 0 && qx < DD)
                acc = fmaf(kw[j + 3], sy[r * 128 + qx], acc);
        }
        out[slab + (size_t)(y0 + r) * DD + xx] = acc;
    }
}

extern "C" void kernel_launch(void* const* d_in, const int* in_sizes, int n_in,
                              void* d_out, int out_size, void* d_ws, size_t ws_size,
                              hipStream_t stream) {
    const float* x   = (const float*)d_in[0];
    const float* w0  = (const float*)d_in[1];
    const float* b0  = (const float*)d_in[2];
    const float* w1  = (const float*)d_in[3];
    const float* b1  = (const float*)d_in[4];
    const float* w2  = (const float*)d_in[5];
    const float* b2  = (const float*)d_in[6];
    const float* w3  = (const float*)d_in[7];
    const float* b3  = (const float*)d_in[8];
    const float* w4  = (const float*)d_in[9];
    const float* b4  = (const float*)d_in[10];
    const float* wc  = (const float*)d_in[11];
    const float* bc  = (const float*)d_in[12];
    const float* wv  = (const float*)d_in[13];
    const float* bv  = (const float*)d_in[14];
    const float* c0  = (const float*)d_in[15];
    const float* v0  = (const float*)d_in[16];

    float* out = (float*)d_out;
    float4* posval = (float4*)d_out;                  // [NB][NV] float4 = 8 MiB
    float* h4 = out + 4 * 1024 * 1024;                // at +16 MiB
    float* hA = h4 + 2048;
    float* hB = hA + 2048;

    // ws[0..64MB): blur intermediate (written by blur-z AFTER the splat chain).
    // Control data must survive blur-z's writes iff the masked-blur path is on,
    // so place it past 64MB when ws allows; else fall back (unmasked blurs).
    const int maskon = (ws_size >= (65ull << 20)) ? 1 : 0;
    const size_t ctrl_off = maskon ? (64ull << 20) : (48ull << 20);
    float4* sorted = (float4*)d_ws;                   // consumed before blur-z
    unsigned* binCount  = (unsigned*)((char*)d_ws + ctrl_off);
    unsigned* gmask     = binCount + NBIN_TOT;        // 512 cells
    unsigned* binStart  = gmask + NMASK;              // NBIN_TOT+1
    unsigned* binCursor = binStart + NBIN_TOT + 1;

    hipMemsetAsync(binCount, 0, (NBIN_TOT + NMASK) * sizeof(unsigned), stream);

    // SIREN MLP: 5 per-layer kernels, 4 blocks each (proven r6 chain)
    k_layer<LAT, 0><<<4, 256, 0, stream>>>(x,  w0, b0, hA);
    k_layer<HID, 1><<<4, 256, 0, stream>>>(hA, w1, b1, hB);
    k_layer<HID, 1><<<4, 256, 0, stream>>>(hB, w2, b2, hA);
    k_layer<HID, 1><<<4, 256, 0, stream>>>(hA, w3, b3, hB);
    k_layer<HID, 2><<<4, 256, 0, stream>>>(hB, w4, b4, h4);

    k_heads<<<NV / 64, 256, 0, stream>>>(h4, wc, bc, wv, bv, c0, v0, posval);

    k_count<<<256, 256, 0, stream>>>(posval, binCount, gmask);
    k_scan<<<1, 1024, 0, stream>>>(binCount, binStart, binCursor);
    k_scatter<<<256, 256, 0, stream>>>(posval, binCursor, sorted);
    k_binsplat<<<NBIN_TOT, 256, 0, stream>>>(sorted, binStart, gmask, maskon, out);

    const int nblk = (NB * D3) / 256;   // 65536
    k_blur_z<<<nblk, 256, 0, stream>>>(out, (float*)d_ws, gmask, maskon);
    k_blur_yx<<<NB * 512, 256, 0, stream>>>((float*)d_ws, out, gmask, maskon);
}

// Round 14
// 293.310 us; speedup vs baseline: 1.3668x; 1.0442x over previous
//
#include <hip/hip_runtime.h>
#include <hip/hip_bf16.h>

#define DD 128
#define D3 (DD*DD*DD)      // 2097152
#define NB 8               // batch
#define NV 65536           // points
#define HID 256
#define LAT 128

// bricks: 32x8x4 voxels -> 2048 per batch, 16384 total
#define NBIN 2048
#define NBIN_TOT (NBIN*NB)
#define NMASK 512          // [batch][zc 0..7][yc 0..7], 16-voxel cells in y,z

// round-to-nearest-even f32 -> bf16, returned as the (exactly representable) f32 value
__device__ __forceinline__ float rbf(float x) {
    unsigned u = __float_as_uint(x);
    unsigned r = (u + 0x7fffu + ((u >> 16) & 1u)) & 0xFFFF0000u;
    return __uint_as_float(r);
}

// -------- SIREN layer: 4 blocks x 1024 threads, 16-way K-split (short chains) ------
// thread = (col cl 0..63, k-slice ks 0..15); 16 (or 8) serial weight loads/thread.
template<int K, int MODE>
__global__ __launch_bounds__(1024) void k_layer(
    const float* __restrict__ in, const float* __restrict__ w,
    const float* __restrict__ bias, float* __restrict__ outp)
{
    __shared__ float in_s[NB * K];            // <= 8 KB
    __shared__ float part[16 * 64 * 9];       // 36 KB, stride-9 pad (conflict-free)
    const int tid = threadIdx.x;
    for (int i = tid; i < NB * K; i += 1024) in_s[i] = rbf(in[i]);
    __syncthreads();

    const int cl = tid & 63;                  // column (wave-contiguous)
    const int ks = tid >> 6;                  // k-slice 0..15 (wave-uniform)
    const int col = blockIdx.x * 64 + cl;

    float acc[NB];
    #pragma unroll
    for (int b = 0; b < NB; ++b) acc[b] = 0.f;

    const int k0 = ks * (K / 16);
    #pragma unroll 8
    for (int k = k0; k < k0 + K / 16; ++k) {
        float wk = rbf(w[k * HID + col]);     // 256B/wave coalesced
        #pragma unroll
        for (int b = 0; b < NB; ++b) acc[b] = fmaf(in_s[b * K + k], wk, acc[b]);
    }

    float* pp = part + (ks * 64 + cl) * 9;
    #pragma unroll
    for (int b = 0; b < NB; ++b) pp[b] = acc[b];
    __syncthreads();

    if (tid < 512) {                          // 512 outputs: 64 cols x 8 batches
        const int c2 = tid >> 3, b = tid & 7;
        const int gcol = blockIdx.x * 64 + c2;
        float s = 0.f;
        #pragma unroll
        for (int kk = 0; kk < 16; ++kk) s += part[(kk * 64 + c2) * 9 + b];
        float t = rbf(s);
        t = rbf(t + rbf(bias[gcol]));
        if (MODE == 0) {
            t = rbf(30.0f * t);
            t = rbf(sinf(t));
        } else if (MODE == 1) {
            float r = rbf(in_s[b * K + gcol] + t);
            t = rbf(sinf(r));
        }
        outp[b * HID + gcol] = t;
    }
}

// ------ heads: staged GEMV, 3-buffer rotation, raw barrier (no vmcnt drain) --------
// 1024 blocks x 256 threads (4/CU, 32 KB LDS). Stage = 8 k-rows. Loads for stage
// s+3 issued at iter s -> ds-written at iter s+2 (compiler emits COUNTED vmcnt for
// those regs); barriers wait lgkmcnt only, so global loads age 2 compute phases
// and ~64 KB/CU stays in flight.
#define PSTR 17
__global__ __launch_bounds__(256, 4) void k_heads(
    const float* __restrict__ h4,
    const float* __restrict__ wc, const float* __restrict__ bc,
    const float* __restrict__ wv, const float* __restrict__ bv,
    const float* __restrict__ coords0, const float* __restrict__ values0,
    float4* __restrict__ posval)
{
    __shared__ float hsT[HID * NB];                      // 8 KB [k][b]
    __shared__ __align__(16) char uni[3 * 512 * 16];     // 24 KB: 3 bufs x 8 KB
    float4 (*buf)[512] = reinterpret_cast<float4(*)[512]>(uni);
    float* part = reinterpret_cast<float*>(uni);         // 17.4 KB epilogue overlay

    const int tid = threadIdx.x;
    const int blk = blockIdx.x;
    const int p   = tid & 63;
    const int ks  = tid >> 6;

    for (int i = tid; i < NB * HID; i += 256) {
        int b = i >> 8, k = i & 255;
        hsT[k * 8 + b] = h4[b * HID + k];
    }

    const float4* wc4 = reinterpret_cast<const float4*>(wc);
    const float4* wv4 = reinterpret_cast<const float4*>(wv);

    // slot geometry (r12 verbatim): 512 f4/stage: 0..383 wc, 384..511 wv
    size_t base0, base1, step1;
    {
        int r = tid / 48, c = tid - r * 48;
        base0 = (size_t)((r >> 1) * 64 + (r & 1)) * 49152 + (size_t)blk * 48 + c;
    }
    const float4* src1;
    if (tid < 128) {
        int t1 = tid + 256;
        int r = t1 / 48, c = t1 - r * 48;
        base1 = (size_t)((r >> 1) * 64 + (r & 1)) * 49152 + (size_t)blk * 48 + c;
        src1 = wc4; step1 = 2 * 49152;
    } else {
        int u = tid - 128;
        int r = u >> 4, c = u & 15;
        base1 = (size_t)((r >> 1) * 64 + (r & 1)) * 16384 + (size_t)blk * 16 + c;
        src1 = wv4; step1 = 2 * 16384;
    }
    const size_t step0 = 2 * 49152;
    const int d0 = tid, d1 = tid + 256;

    float acc[4][8];
    #pragma unroll
    for (int c = 0; c < 4; ++c)
        #pragma unroll
        for (int b = 0; b < NB; ++b) acc[c][b] = 0.f;

    const float4* h4v = reinterpret_cast<const float4*>(hsT);

    // lgkm-only barrier: LDS ops drained + workgroup sync, global loads stay in flight
    #define SBAR() do { \
        asm volatile("s_waitcnt lgkmcnt(0)" ::: "memory"); \
        __builtin_amdgcn_s_barrier(); \
        __builtin_amdgcn_sched_barrier(0); \
    } while (0)

    #define COMPUTE(s_, bi_) { \
        const float* wcsF = reinterpret_cast<const float*>(&buf[bi_][0]); \
        const float* wvsF = reinterpret_cast<const float*>(&buf[bi_][384]); \
        _Pragma("unroll") \
        for (int j = 0; j < 2; ++j) { \
            const int r = ks * 2 + j; \
            const int k = ks * 64 + 2 * (s_) + j; \
            float c0 = wcsF[r * 192 + 3 * p]; \
            float c1 = wcsF[r * 192 + 3 * p + 1]; \
            float c2 = wcsF[r * 192 + 3 * p + 2]; \
            float vv = wvsF[r * 64 + p]; \
            float4 hA_ = h4v[k * 2], hB_ = h4v[k * 2 + 1]; \
            float hb[8] = {hA_.x, hA_.y, hA_.z, hA_.w, hB_.x, hB_.y, hB_.z, hB_.w}; \
            _Pragma("unroll") \
            for (int b = 0; b < NB; ++b) { \
                acc[0][b] = fmaf(hb[b], c0, acc[0][b]); \
                acc[1][b] = fmaf(hb[b], c1, acc[1][b]); \
                acc[2][b] = fmaf(hb[b], c2, acc[2][b]); \
                acc[3][b] = fmaf(hb[b], vv, acc[3][b]); \
            } \
        } \
    }

    // regset rotation: slot(load L(s+3)) = s%3, slot(write R(s+1)) = (s+1)%3
    float4 Ra0, Ra1, Rb0, Rb1, Rc0, Rc1;
    Ra0 = wc4[base0];                 Ra1 = src1[base1];                 // L0 -> a
    Rb0 = wc4[base0 + step0];         Rb1 = src1[base1 + step1];         // L1 -> b
    Rc0 = wc4[base0 + 2 * step0];     Rc1 = src1[base1 + 2 * step1];     // L2 -> c
    buf[0][d0] = Ra0; buf[0][d1] = Ra1;          // stage 0 (vmcnt counted by compiler)
    SBAR();

    for (int t = 0; t < 11; ++t) {
        {   // s = 3t: compute buf0; write Rb->buf1; load L(s+3)->Ra
            const int s = 3 * t;
            COMPUTE(s, 0);
            if (s <= 30) { buf[1][d0] = Rb0; buf[1][d1] = Rb1; }
            if (s <= 28) {
                Ra0 = wc4[base0 + (size_t)(s + 3) * step0];
                Ra1 = src1[base1 + (size_t)(s + 3) * step1];
            }
            SBAR();
        }
        if (3 * t + 1 < 32) {   // s = 3t+1: compute buf1; write Rc->buf2; load->Rb
            const int s = 3 * t + 1;
            COMPUTE(s, 1);
            if (s <= 30) { buf[2][d0] = Rc0; buf[2][d1] = Rc1; }
            if (s <= 28) {
                Rb0 = wc4[base0 + (size_t)(s + 3) * step0];
                Rb1 = src1[base1 + (size_t)(s + 3) * step1];
            }
            SBAR();
        }
        if (3 * t + 2 < 32) {   // s = 3t+2: compute buf2; write Ra->buf0; load->Rc
            const int s = 3 * t + 2;
            COMPUTE(s, 2);
            if (s <= 30) { buf[0][d0] = Ra0; buf[0][d1] = Ra1; }
            if (s <= 28) {
                Rc0 = wc4[base0 + (size_t)(s + 3) * step0];
                Rc1 = src1[base1 + (size_t)(s + 3) * step1];
            }
            SBAR();
        }
    }
    #undef COMPUTE
    #undef SBAR
    __syncthreads();                     // full drain before part[] overlay

    const int bp = ks;
    const int v  = blk * 64 + p;
    const float factor = 0.5f * DD;
    float* pp = part + (ks * 64 + p) * PSTR;

    #pragma unroll
    for (int phase = 0; phase < 2; ++phase) {
        if (phase) __syncthreads();
        #pragma unroll
        for (int q = 0; q < 4; ++q) {
            int b = phase * 4 + q;
            pp[q * 4 + 0] = acc[0][b]; pp[q * 4 + 1] = acc[1][b];
            pp[q * 4 + 2] = acc[2][b]; pp[q * 4 + 3] = acc[3][b];
        }
        __syncthreads();
        {
            const int b = phase * 4 + bp;
            float A0 = 0.f, A1 = 0.f, A2 = 0.f, A3 = 0.f;
            #pragma unroll
            for (int k2 = 0; k2 < 4; ++k2) {
                const float* rp = part + (k2 * 64 + p) * PSTR + bp * 4;
                A0 += rp[0]; A1 += rp[1]; A2 += rp[2]; A3 += rp[3];
            }
            float px = factor * (coords0[3 * v]     + (A0 + bc[3 * v]))     + factor;
            float py = factor * (coords0[3 * v + 1] + (A1 + bc[3 * v + 1])) + factor;
            float pz = factor * (coords0[3 * v + 2] + (A2 + bc[3 * v + 2])) + factor;
            float val = fmaxf(values0[v] + (A3 + bv[v]), 0.f);
            posval[(size_t)b * NV + v] = make_float4(px, py, pz, val);
        }
    }
}

// ----------------------------- binning helpers -------------------------------------
__device__ __forceinline__ bool point_base(float4 q, int& ix, int& iy, int& iz) {
    if (q.w == 0.f) return false;
    ix = (int)floorf(q.x); iy = (int)floorf(q.y); iz = (int)floorf(q.z);
    return ix >= -1 && ix <= 127 && iy >= -1 && iy <= 127 && iz >= -1 && iz <= 127;
}

__device__ __forceinline__ void brick_span(int ix, int iy, int iz,
                                           int& bx0, int& bx1, int& by0, int& by1,
                                           int& bz0, int& bz1) {
    bx0 = (ix < 0 ? 0 : ix) >> 5;  bx1 = (ix + 1 > 127 ? 127 : ix + 1) >> 5;
    by0 = (iy < 0 ? 0 : iy) >> 3;  by1 = (iy + 1 > 127 ? 127 : iy + 1) >> 3;
    bz0 = (iz < 0 ? 0 : iz) >> 2;  bz1 = (iz + 1 > 127 ? 127 : iz + 1) >> 2;
}

// --------------- k_count: brick histogram + (y,z) influence mask ------------------
__global__ __launch_bounds__(256) void k_count(const float4* __restrict__ posval,
                                               unsigned* __restrict__ binCount,
                                               unsigned* __restrict__ gmask)
{
    __shared__ unsigned hist[NBIN];
    __shared__ unsigned lmask[64];
    const int tid = threadIdx.x;
    const int batch = blockIdx.x >> 5;
    const size_t base = (size_t)batch * NV + (blockIdx.x & 31) * 2048;
    for (int i = tid; i < NBIN; i += 256) hist[i] = 0;
    if (tid < 64) lmask[tid] = 0;
    __syncthreads();
    #pragma unroll
    for (int j = 0; j < 8; ++j) {
        float4 q = posval[base + j * 256 + tid];
        int ix, iy, iz;
        if (point_base(q, ix, iy, iz)) {
            int bx0, bx1, by0, by1, bz0, bz1;
            brick_span(ix, iy, iz, bx0, bx1, by0, by1, bz0, bz1);
            for (int bz = bz0; bz <= bz1; ++bz)
                for (int by = by0; by <= by1; ++by)
                    for (int bx = bx0; bx <= bx1; ++bx)
                        atomicAdd(&hist[(bz * 16 + by) * 4 + bx], 1u);
            int ylo = iy - 3 < 0 ? 0 : iy - 3, yhi = iy + 4 > 127 ? 127 : iy + 4;
            int zlo = iz - 3 < 0 ? 0 : iz - 3, zhi = iz + 4 > 127 ? 127 : iz + 4;
            for (int zc = zlo >> 4; zc <= zhi >> 4; ++zc)
                for (int yc = ylo >> 4; yc <= yhi >> 4; ++yc)
                    lmask[zc * 8 + yc] = 1u;
        }
    }
    __syncthreads();
    for (int i = tid; i < NBIN; i += 256) {
        unsigned c = hist[i];
        if (c) atomicAdd(&binCount[batch * NBIN + i], c);
    }
    if (tid < 64 && lmask[tid]) atomicOr(&gmask[batch * 64 + tid], 1u);
}

// --------------- k_scan: exclusive scan over 16384 bins (single block) -------------
__global__ __launch_bounds__(1024) void k_scan(const unsigned* __restrict__ cnt,
                                               unsigned* __restrict__ start,
                                               unsigned* __restrict__ cursor)
{
    __shared__ unsigned partial[1024];
    const int t = threadIdx.x;
    const int base = t * 16;
    unsigned s = 0;
    #pragma unroll
    for (int j = 0; j < 16; ++j) s += cnt[base + j];
    partial[t] = s;
    __syncthreads();
    for (int off = 1; off < 1024; off <<= 1) {
        unsigned mine = partial[t];
        unsigned add = (t >= off) ? partial[t - off] : 0u;
        __syncthreads();
        partial[t] = mine + add;
        __syncthreads();
    }
    unsigned run = (t > 0) ? partial[t - 1] : 0u;
    #pragma unroll
    for (int j = 0; j < 16; ++j) {
        start[base + j] = run;
        cursor[base + j] = run;
        run += cnt[base + j];
    }
    if (t == 1023) start[NBIN_TOT] = partial[1023];
}

// -------- k_scatter: copy each point into every touched brick's contiguous range ----
__global__ __launch_bounds__(256) void k_scatter(const float4* __restrict__ posval,
                                                 unsigned* __restrict__ binCursor,
                                                 float4* __restrict__ sorted)
{
    __shared__ unsigned hist[NBIN];
    __shared__ unsigned bbase[NBIN];
    const int tid = threadIdx.x;
    const int batch = blockIdx.x >> 5;
    const size_t base = (size_t)batch * NV + (blockIdx.x & 31) * 2048;
    for (int i = tid; i < NBIN; i += 256) hist[i] = 0;
    __syncthreads();

    float4 q[8];
    #pragma unroll
    for (int j = 0; j < 8; ++j) {
        q[j] = posval[base + j * 256 + tid];
        int ix, iy, iz;
        if (point_base(q[j], ix, iy, iz)) {
            int bx0, bx1, by0, by1, bz0, bz1;
            brick_span(ix, iy, iz, bx0, bx1, by0, by1, bz0, bz1);
            for (int bz = bz0; bz <= bz1; ++bz)
                for (int by = by0; by <= by1; ++by)
                    for (int bx = bx0; bx <= bx1; ++bx)
                        atomicAdd(&hist[(bz * 16 + by) * 4 + bx], 1u);
        }
    }
    __syncthreads();
    for (int i = tid; i < NBIN; i += 256) {
        unsigned c = hist[i];
        bbase[i] = c ? atomicAdd(&binCursor[batch * NBIN + i], c) : 0u;
    }
    __syncthreads();
    for (int i = tid; i < NBIN; i += 256) hist[i] = 0;
    __syncthreads();
    #pragma unroll
    for (int j = 0; j < 8; ++j) {
        int ix, iy, iz;
        if (point_base(q[j], ix, iy, iz)) {
            int bx0, bx1, by0, by1, bz0, bz1;
            brick_span(ix, iy, iz, bx0, bx1, by0, by1, bz0, bz1);
            for (int bz = bz0; bz <= bz1; ++bz)
                for (int by = by0; by <= by1; ++by)
                    for (int bx = bx0; bx <= bx1; ++bx) {
                        int bin = (bz * 16 + by) * 4 + bx;
                        unsigned r = atomicAdd(&hist[bin], 1u);
                        sorted[bbase[bin] + r] = q[j];
                    }
        }
    }
}

// -------- k_binsplat: one block per 32x8x4 brick; mask-gated; LDS accumulate -------
__global__ __launch_bounds__(256) void k_binsplat(const float4* __restrict__ sorted,
                                                  const unsigned* __restrict__ binStart,
                                                  const unsigned* __restrict__ gmask,
                                                  int maskon,
                                                  float* __restrict__ grid)
{
    __shared__ float brick[4 * 8 * 32];
    const int tid = threadIdx.x;
    const int bid = blockIdx.x;
    const int bx = bid & 3;
    const int by = (bid >> 2) & 15;
    const int bz = (bid >> 6) & 31;
    const int batch = bid >> 11;
    const int x0 = bx << 5, y0 = by << 3, z0 = bz << 2;

    if (maskon && gmask[batch * 64 + (bz >> 2) * 8 + (by >> 1)] == 0u) return;

    const unsigned s = binStart[bid], e = binStart[bid + 1];

    const int vx4 = tid & 7, cy = (tid >> 3) & 7, cz = tid >> 6;
    const size_t o = (size_t)batch * D3 + (size_t)(z0 + cz) * (DD * DD)
                   + (size_t)(y0 + cy) * DD + x0 + vx4 * 4;

    if (s == e) {
        *reinterpret_cast<float4*>(grid + o) = make_float4(0.f, 0.f, 0.f, 0.f);
        return;
    }

    for (int i = tid; i < 1024; i += 256) brick[i] = 0.f;
    __syncthreads();

    for (unsigned i = s + tid; i < e; i += 256) {
        float4 q = sorted[i];
        float fx = floorf(q.x), fy = floorf(q.y), fz = floorf(q.z);
        int vx = (int)fx - x0, vy = (int)fy - y0, vz = (int)fz - z0;
        float gx = q.x - fx, gy = q.y - fy, gz = q.z - fz;
        float wx0 = 1.f - gx, wy0 = 1.f - gy, wz0 = 1.f - gz;
        #pragma unroll
        for (int oz = 0; oz < 2; ++oz)
        #pragma unroll
        for (int oy = 0; oy < 2; ++oy)
        #pragma unroll
        for (int ox = 0; ox < 2; ++ox) {
            int cxx = vx + ox, cyy = vy + oy, czz = vz + oz;
            if ((unsigned)cxx < 32u && (unsigned)cyy < 8u && (unsigned)czz < 4u) {
                float w = ((ox ? gx : wx0) * (oy ? gy : wy0)) * (oz ? gz : wz0);
                atomicAdd(&brick[(czz * 8 + cyy) * 32 + cxx], q.w * w);
            }
        }
    }
    __syncthreads();

    *reinterpret_cast<float4*>(grid + o) =
        *reinterpret_cast<const float4*>(&brick[(cz * 8 + cy) * 32 + vx4 * 4]);
}

// ---------------- z blur, mask-gated: skip unmarked blocks entirely ----------------
__global__ __launch_bounds__(256) void k_blur_z(const float* __restrict__ in,
                                                float* __restrict__ out,
                                                const unsigned* __restrict__ gmask,
                                                int maskon)
{
    const int b = blockIdx.x;
    const int batch = b >> 13;
    const int z = (b >> 6) & 127;
    const int y0 = (b * 2) & 127;
    const long i = (long)b * 256 + threadIdx.x;

    unsigned okbits = 0x7fu;
    if (maskon) {
        if (gmask[batch * 64 + (z >> 4) * 8 + (y0 >> 4)] == 0u) return;
        okbits = 0u;
        #pragma unroll
        for (int j = -3; j <= 3; ++j) {
            int zj = z + j;
            if (zj >= 0 && zj < DD && gmask[batch * 64 + (zj >> 4) * 8 + (y0 >> 4)])
                okbits |= 1u << (j + 3);
        }
    }

    const double e1 = 0.6065306597126334, e2 = 0.1353352832366127, e3 = 0.011108996538242306;
    const double s = 1.0 + 2.0 * (e1 + e2 + e3);
    const float kw[7] = {(float)(e3 / s), (float)(e2 / s), (float)(e1 / s), (float)(1.0 / s),
                         (float)(e1 / s), (float)(e2 / s), (float)(e3 / s)};

    float acc = 0.f;
    #pragma unroll
    for (int j = -3; j <= 3; ++j) {
        int q = z + j;
        if (q >= 0 && q < DD && ((okbits >> (j + 3)) & 1u))
            acc = fmaf(kw[j + 3], in[i + ((long)j << 14)], acc);
    }
    out[i] = acc;
}

// ------------- fused y+x blur, mask-gated zero-fast-path + halo substitution -------
__global__ __launch_bounds__(256) void k_blur_yx(const float* __restrict__ in,
                                                 float* __restrict__ out,
                                                 const unsigned* __restrict__ gmask,
                                                 int maskon)
{
    __shared__ float sin_[38 * 128];
    __shared__ float sy[32 * 128];
    __shared__ unsigned mrow[8];

    const double e1 = 0.6065306597126334, e2 = 0.1353352832366127, e3 = 0.011108996538242306;
    const double ss = 1.0 + 2.0 * (e1 + e2 + e3);
    const float kw[7] = {(float)(e3 / ss), (float)(e2 / ss), (float)(e1 / ss), (float)(1.0 / ss),
                         (float)(e1 / ss), (float)(e2 / ss), (float)(e3 / ss)};

    const int tid = threadIdx.x;
    const int bid = blockIdx.x;
    const int ytile = bid & 3;
    const int z = (bid >> 2) & 127;
    const int batch = bid >> 9;
    const int y0 = ytile << 5;
    const size_t slab = (size_t)batch * D3 + (size_t)z * (DD * DD);

    if (maskon) {
        if (tid < 8) mrow[tid] = gmask[batch * 64 + (z >> 4) * 8 + tid];
        __syncthreads();
        const int yc0 = y0 >> 4;
        if (mrow[yc0] == 0u && mrow[yc0 + 1] == 0u) {
            const float4 z4 = make_float4(0.f, 0.f, 0.f, 0.f);
            for (int i = tid; i < 1024; i += 256) {
                int r = i >> 5, xq = i & 31;
                *reinterpret_cast<float4*>(&out[slab + (size_t)(y0 + r) * DD + xq * 4]) = z4;
            }
            return;
        }
    }

    for (int i = tid; i < 38 * 128; i += 256) {
        int row = i >> 7, xx = i & 127;
        int gy = y0 + row - 3;
        bool ok = gy >= 0 && gy < DD && (!maskon || mrow[gy >> 4]);
        sin_[i] = ok ? in[slab + (size_t)gy * DD + xx] : 0.f;
    }
    __syncthreads();

    for (int i = tid; i < 32 * 128; i += 256) {
        int r = i >> 7, xx = i & 127;
        float acc = 0.f;
        #pragma unroll
        for (int j = 0; j < 7; ++j)
            acc = fmaf(kw[j], sin_[(r + j) * 128 + xx], acc);
        sy[i] = acc;
    }
    __syncthreads();

    for (int i = tid; i < 32 * 128; i += 256) {
        int r = i >> 7, xx = i & 127;
        float acc = 0.f;
        #pragma unroll
        for (int j = -3; j <= 3; ++j) {
            int qx = xx + j;
            if (qx >= 0 && qx < DD)
                acc = fmaf(kw[j + 3], sy[r * 128 + qx], acc);
        }
        out[slab + (size_t)(y0 + r) * DD + xx] = acc;
    }
}

extern "C" void kernel_launch(void* const* d_in, const int* in_sizes, int n_in,
                              void* d_out, int out_size, void* d_ws, size_t ws_size,
                              hipStream_t stream) {
    const float* x   = (const float*)d_in[0];
    const float* w0  = (const float*)d_in[1];
    const float* b0  = (const float*)d_in[2];
    const float* w1  = (const float*)d_in[3];
    const float* b1  = (const float*)d_in[4];
    const float* w2  = (const float*)d_in[5];
    const float* b2  = (const float*)d_in[6];
    const float* w3  = (const float*)d_in[7];
    const float* b3  = (const float*)d_in[8];
    const float* w4  = (const float*)d_in[9];
    const float* b4  = (const float*)d_in[10];
    const float* wc  = (const float*)d_in[11];
    const float* bc  = (const float*)d_in[12];
    const float* wv  = (const float*)d_in[13];
    const float* bv  = (const float*)d_in[14];
    const float* c0  = (const float*)d_in[15];
    const float* v0  = (const float*)d_in[16];

    float* out = (float*)d_out;
    float4* posval = (float4*)d_out;                  // [NB][NV] float4 = 8 MiB
    float* h4 = out + 4 * 1024 * 1024;                // at +16 MiB
    float* hA = h4 + 2048;
    float* hB = hA + 2048;

    const int maskon = (ws_size >= (65ull << 20)) ? 1 : 0;
    const size_t ctrl_off = maskon ? (64ull << 20) : (48ull << 20);
    float4* sorted = (float4*)d_ws;
    unsigned* binCount  = (unsigned*)((char*)d_ws + ctrl_off);
    unsigned* gmask     = binCount + NBIN_TOT;
    unsigned* binStart  = gmask + NMASK;
    unsigned* binCursor = binStart + NBIN_TOT + 1;

    hipMemsetAsync(binCount, 0, (NBIN_TOT + NMASK) * sizeof(unsigned), stream);

    // SIREN MLP: 5 per-layer kernels, 4 blocks x 1024 threads (16-way K-split)
    k_layer<LAT, 0><<<4, 1024, 0, stream>>>(x,  w0, b0, hA);
    k_layer<HID, 1><<<4, 1024, 0, stream>>>(hA, w1, b1, hB);
    k_layer<HID, 1><<<4, 1024, 0, stream>>>(hB, w2, b2, hA);
    k_layer<HID, 1><<<4, 1024, 0, stream>>>(hA, w3, b3, hB);
    k_layer<HID, 2><<<4, 1024, 0, stream>>>(hB, w4, b4, h4);

    k_heads<<<NV / 64, 256, 0, stream>>>(h4, wc, bc, wv, bv, c0, v0, posval);

    k_count<<<256, 256, 0, stream>>>(posval, binCount, gmask);
    k_scan<<<1, 1024, 0, stream>>>(binCount, binStart, binCursor);
    k_scatter<<<256, 256, 0, stream>>>(posval, binCursor, sorted);
    k_binsplat<<<NBIN_TOT, 256, 0, stream>>>(sorted, binStart, gmask, maskon, out);

    const int nblk = (NB * D3) / 256;   // 65536
    k_blur_z<<<nblk, 256, 0, stream>>>(out, (float*)d_ws, gmask, maskon);
    k_blur_yx<<<NB * 512, 256, 0, stream>>>((float*)d_ws, out, gmask, maskon);
}

// Round 15
// 276.121 us; speedup vs baseline: 1.4519x; 1.0623x over previous
//
#include <hip/hip_runtime.h>
#include <hip/hip_bf16.h>

#define DD 128
#define D3 (DD*DD*DD)      // 2097152
#define NB 8               // batch
#define NV 65536           // points
#define HID 256
#define LAT 128

// bricks: 32x8x4 voxels -> 2048 per batch, 16384 total
#define NBIN 2048
#define NBIN_TOT (NBIN*NB)
#define NMASK 512          // [batch][zc 0..7][yc 0..7], 16-voxel cells in y,z

// round-to-nearest-even f32 -> bf16, returned as the (exactly representable) f32 value
__device__ __forceinline__ float rbf(float x) {
    unsigned u = __float_as_uint(x);
    unsigned r = (u + 0x7fffu + ((u >> 16) & 1u)) & 0xFFFF0000u;
    return __uint_as_float(r);
}

// -------- SIREN layer: 4 blocks x 1024 threads, 16-way K-split (r14 verbatim) ------
template<int K, int MODE>
__global__ __launch_bounds__(1024) void k_layer(
    const float* __restrict__ in, const float* __restrict__ w,
    const float* __restrict__ bias, float* __restrict__ outp)
{
    __shared__ float in_s[NB * K];            // <= 8 KB
    __shared__ float part[16 * 64 * 9];       // 36 KB, stride-9 pad
    const int tid = threadIdx.x;
    for (int i = tid; i < NB * K; i += 1024) in_s[i] = rbf(in[i]);
    __syncthreads();

    const int cl = tid & 63;
    const int ks = tid >> 6;
    const int col = blockIdx.x * 64 + cl;

    float acc[NB];
    #pragma unroll
    for (int b = 0; b < NB; ++b) acc[b] = 0.f;

    const int k0 = ks * (K / 16);
    #pragma unroll 8
    for (int k = k0; k < k0 + K / 16; ++k) {
        float wk = rbf(w[k * HID + col]);
        #pragma unroll
        for (int b = 0; b < NB; ++b) acc[b] = fmaf(in_s[b * K + k], wk, acc[b]);
    }

    float* pp = part + (ks * 64 + cl) * 9;
    #pragma unroll
    for (int b = 0; b < NB; ++b) pp[b] = acc[b];
    __syncthreads();

    if (tid < 512) {
        const int c2 = tid >> 3, b = tid & 7;
        const int gcol = blockIdx.x * 64 + c2;
        float s = 0.f;
        #pragma unroll
        for (int kk = 0; kk < 16; ++kk) s += part[(kk * 64 + c2) * 9 + b];
        float t = rbf(s);
        t = rbf(t + rbf(bias[gcol]));
        if (MODE == 0) {
            t = rbf(30.0f * t);
            t = rbf(sinf(t));
        } else if (MODE == 1) {
            float r = rbf(in_s[b * K + gcol] + t);
            t = rbf(sinf(r));
        }
        outp[b * HID + gcol] = t;
    }
}

// ------ heads: r12 dbuf staged GEMV + XCD swizzle + control-buffer zeroing ---------
#define PSTR 17
__global__ __launch_bounds__(256, 4) void k_heads(
    const float* __restrict__ h4,
    const float* __restrict__ wc, const float* __restrict__ bc,
    const float* __restrict__ wv, const float* __restrict__ bv,
    const float* __restrict__ coords0, const float* __restrict__ values0,
    float4* __restrict__ posval,
    unsigned* __restrict__ zeroBuf)      // binCount..gmask span, zeroed here
{
    __shared__ float hsT[HID * NB];                         // 8 KB [k][b]
    __shared__ __align__(16) char uni[4 * 64 * PSTR * 4];   // 17.4 KB union
    float4 (*buf)[512] = reinterpret_cast<float4(*)[512]>(uni);  // dbuf 2x8KB
    float* part = reinterpret_cast<float*>(uni);                 // epilogue overlay

    const int tid = threadIdx.x;
    // bijective XCD swizzle (nwg=1024, 1024%8==0): xcd-contiguous chunks
    const int blk = ((blockIdx.x & 7) << 7) + (blockIdx.x >> 3);
    const int p   = tid & 63;            // point-in-block (lane)
    const int ks  = tid >> 6;            // k-slice = wave id (uniform)

    // zero binCount+gmask (16896 words) before k_count (runs after heads completes)
    {
        int zi = blockIdx.x * 256 + tid;
        if (zi < NBIN_TOT + NMASK) zeroBuf[zi] = 0u;
    }

    for (int i = tid; i < NB * HID; i += 256) {
        int b = i >> 8, k = i & 255;
        hsT[k * 8 + b] = h4[b * HID + k];
    }

    const float4* wc4 = reinterpret_cast<const float4*>(wc);
    const float4* wv4 = reinterpret_cast<const float4*>(wv);

    // slot geometry: stage has 512 f4 slots: 0..383 wc, 384..511 wv
    size_t base0, base1, step1;
    {
        int r = tid / 48, c = tid - r * 48;
        base0 = (size_t)((r >> 1) * 64 + (r & 1)) * 49152 + (size_t)blk * 48 + c;
    }
    const float4* src1;
    if (tid < 128) {
        int t1 = tid + 256;
        int r = t1 / 48, c = t1 - r * 48;
        base1 = (size_t)((r >> 1) * 64 + (r & 1)) * 49152 + (size_t)blk * 48 + c;
        src1 = wc4; step1 = 2 * 49152;
    } else {
        int u = tid - 128;
        int r = u >> 4, c = u & 15;
        base1 = (size_t)((r >> 1) * 64 + (r & 1)) * 16384 + (size_t)blk * 16 + c;
        src1 = wv4; step1 = 2 * 16384;
    }
    const size_t step0 = 2 * 49152;
    const int d0 = tid, d1 = tid + 256;

    float acc[4][8];                     // [x,y,z,val][batch]
    #pragma unroll
    for (int c = 0; c < 4; ++c)
        #pragma unroll
        for (int b = 0; b < NB; ++b) acc[c][b] = 0.f;

    const float4* h4v = reinterpret_cast<const float4*>(hsT);

    // prologue: stage 0 -> buf0; stage 1 held in R
    float4 R0 = wc4[base0];
    float4 R1 = src1[base1];
    buf[0][d0] = R0; buf[0][d1] = R1;
    R0 = wc4[base0 + step0];
    R1 = src1[base1 + step1];
    __syncthreads();                     // hsT + buf0 visible

    float4 R0n, R1n;
    for (int s = 0; s < 32; ++s) {
        if (s + 2 < 32) {                // issue s+2 BEFORE compute -> latency covered
            R0n = wc4[base0 + (size_t)(s + 2) * step0];
            R1n = src1[base1 + (size_t)(s + 2) * step1];
        }
        const int bi = s & 1;
        const float* wcsF = reinterpret_cast<const float*>(&buf[bi][0]);
        const float* wvsF = reinterpret_cast<const float*>(&buf[bi][384]);
        #pragma unroll
        for (int j = 0; j < 2; ++j) {
            const int r = ks * 2 + j;
            const int k = ks * 64 + 2 * s + j;
            float c0 = wcsF[r * 192 + 3 * p];
            float c1 = wcsF[r * 192 + 3 * p + 1];
            float c2 = wcsF[r * 192 + 3 * p + 2];
            float vv = wvsF[r * 64 + p];
            float4 hA_ = h4v[k * 2], hB_ = h4v[k * 2 + 1];   // uniform broadcast
            float hb[8] = {hA_.x, hA_.y, hA_.z, hA_.w, hB_.x, hB_.y, hB_.z, hB_.w};
            #pragma unroll
            for (int b = 0; b < NB; ++b) {
                acc[0][b] = fmaf(hb[b], c0, acc[0][b]);
                acc[1][b] = fmaf(hb[b], c1, acc[1][b]);
                acc[2][b] = fmaf(hb[b], c2, acc[2][b]);
                acc[3][b] = fmaf(hb[b], vv, acc[3][b]);
            }
        }
        __syncthreads();                 // readers of buf[bi] done
        if (s < 31) {
            buf[bi ^ 1][d0] = R0;        // write stage s+1
            buf[bi ^ 1][d1] = R1;
            R0 = R0n; R1 = R1n;
            __syncthreads();             // buf[bi^1] visible for stage s+1
        }
    }
    __syncthreads();                     // all compute done before part[] overlay

    // cross-slice reduce (two-phase) + epilogue
    const int bp = ks;
    const int v  = blk * 64 + p;
    const float factor = 0.5f * DD;
    float* pp = part + (ks * 64 + p) * PSTR;

    #pragma unroll
    for (int phase = 0; phase < 2; ++phase) {
        if (phase) __syncthreads();
        #pragma unroll
        for (int q = 0; q < 4; ++q) {
            int b = phase * 4 + q;
            pp[q * 4 + 0] = acc[0][b]; pp[q * 4 + 1] = acc[1][b];
            pp[q * 4 + 2] = acc[2][b]; pp[q * 4 + 3] = acc[3][b];
        }
        __syncthreads();
        {
            const int b = phase * 4 + bp;
            float A0 = 0.f, A1 = 0.f, A2 = 0.f, A3 = 0.f;
            #pragma unroll
            for (int k2 = 0; k2 < 4; ++k2) {
                const float* rp = part + (k2 * 64 + p) * PSTR + bp * 4;
                A0 += rp[0]; A1 += rp[1]; A2 += rp[2]; A3 += rp[3];
            }
            float px = factor * (coords0[3 * v]     + (A0 + bc[3 * v]))     + factor;
            float py = factor * (coords0[3 * v + 1] + (A1 + bc[3 * v + 1])) + factor;
            float pz = factor * (coords0[3 * v + 2] + (A2 + bc[3 * v + 2])) + factor;
            float val = fmaxf(values0[v] + (A3 + bv[v]), 0.f);
            posval[(size_t)b * NV + v] = make_float4(px, py, pz, val);
        }
    }
}

// ----------------------------- binning helpers -------------------------------------
__device__ __forceinline__ bool point_base(float4 q, int& ix, int& iy, int& iz) {
    if (q.w == 0.f) return false;
    ix = (int)floorf(q.x); iy = (int)floorf(q.y); iz = (int)floorf(q.z);
    return ix >= -1 && ix <= 127 && iy >= -1 && iy <= 127 && iz >= -1 && iz <= 127;
}

__device__ __forceinline__ void brick_span(int ix, int iy, int iz,
                                           int& bx0, int& bx1, int& by0, int& by1,
                                           int& bz0, int& bz1) {
    bx0 = (ix < 0 ? 0 : ix) >> 5;  bx1 = (ix + 1 > 127 ? 127 : ix + 1) >> 5;
    by0 = (iy < 0 ? 0 : iy) >> 3;  by1 = (iy + 1 > 127 ? 127 : iy + 1) >> 3;
    bz0 = (iz < 0 ? 0 : iz) >> 2;  bz1 = (iz + 1 > 127 ? 127 : iz + 1) >> 2;
}

// --------------- k_count: brick histogram + (y,z) influence mask ------------------
__global__ __launch_bounds__(256) void k_count(const float4* __restrict__ posval,
                                               unsigned* __restrict__ binCount,
                                               unsigned* __restrict__ gmask)
{
    __shared__ unsigned hist[NBIN];
    __shared__ unsigned lmask[64];
    const int tid = threadIdx.x;
    const int batch = blockIdx.x >> 5;
    const size_t base = (size_t)batch * NV + (blockIdx.x & 31) * 2048;
    for (int i = tid; i < NBIN; i += 256) hist[i] = 0;
    if (tid < 64) lmask[tid] = 0;
    __syncthreads();
    #pragma unroll
    for (int j = 0; j < 8; ++j) {
        float4 q = posval[base + j * 256 + tid];
        int ix, iy, iz;
        if (point_base(q, ix, iy, iz)) {
            int bx0, bx1, by0, by1, bz0, bz1;
            brick_span(ix, iy, iz, bx0, bx1, by0, by1, bz0, bz1);
            for (int bz = bz0; bz <= bz1; ++bz)
                for (int by = by0; by <= by1; ++by)
                    for (int bx = bx0; bx <= bx1; ++bx)
                        atomicAdd(&hist[(bz * 16 + by) * 4 + bx], 1u);
            int ylo = iy - 3 < 0 ? 0 : iy - 3, yhi = iy + 4 > 127 ? 127 : iy + 4;
            int zlo = iz - 3 < 0 ? 0 : iz - 3, zhi = iz + 4 > 127 ? 127 : iz + 4;
            for (int zc = zlo >> 4; zc <= zhi >> 4; ++zc)
                for (int yc = ylo >> 4; yc <= yhi >> 4; ++yc)
                    lmask[zc * 8 + yc] = 1u;
        }
    }
    __syncthreads();
    for (int i = tid; i < NBIN; i += 256) {
        unsigned c = hist[i];
        if (c) atomicAdd(&binCount[batch * NBIN + i], c);
    }
    if (tid < 64 && lmask[tid]) atomicOr(&gmask[batch * 64 + tid], 1u);
}

// --------------- k_scan: exclusive scan over 16384 bins (single block) -------------
__global__ __launch_bounds__(1024) void k_scan(const unsigned* __restrict__ cnt,
                                               unsigned* __restrict__ start,
                                               unsigned* __restrict__ cursor)
{
    __shared__ unsigned partial[1024];
    const int t = threadIdx.x;
    const int base = t * 16;
    unsigned s = 0;
    #pragma unroll
    for (int j = 0; j < 16; ++j) s += cnt[base + j];
    partial[t] = s;
    __syncthreads();
    for (int off = 1; off < 1024; off <<= 1) {
        unsigned mine = partial[t];
        unsigned add = (t >= off) ? partial[t - off] : 0u;
        __syncthreads();
        partial[t] = mine + add;
        __syncthreads();
    }
    unsigned run = (t > 0) ? partial[t - 1] : 0u;
    #pragma unroll
    for (int j = 0; j < 16; ++j) {
        start[base + j] = run;
        cursor[base + j] = run;
        run += cnt[base + j];
    }
    if (t == 1023) start[NBIN_TOT] = partial[1023];
}

// -------- k_scatter: copy each point into every touched brick's contiguous range ----
__global__ __launch_bounds__(256) void k_scatter(const float4* __restrict__ posval,
                                                 unsigned* __restrict__ binCursor,
                                                 float4* __restrict__ sorted)
{
    __shared__ unsigned hist[NBIN];
    __shared__ unsigned bbase[NBIN];
    const int tid = threadIdx.x;
    const int batch = blockIdx.x >> 5;
    const size_t base = (size_t)batch * NV + (blockIdx.x & 31) * 2048;
    for (int i = tid; i < NBIN; i += 256) hist[i] = 0;
    __syncthreads();

    float4 q[8];
    #pragma unroll
    for (int j = 0; j < 8; ++j) {
        q[j] = posval[base + j * 256 + tid];
        int ix, iy, iz;
        if (point_base(q[j], ix, iy, iz)) {
            int bx0, bx1, by0, by1, bz0, bz1;
            brick_span(ix, iy, iz, bx0, bx1, by0, by1, bz0, bz1);
            for (int bz = bz0; bz <= bz1; ++bz)
                for (int by = by0; by <= by1; ++by)
                    for (int bx = bx0; bx <= bx1; ++bx)
                        atomicAdd(&hist[(bz * 16 + by) * 4 + bx], 1u);
        }
    }
    __syncthreads();
    for (int i = tid; i < NBIN; i += 256) {
        unsigned c = hist[i];
        bbase[i] = c ? atomicAdd(&binCursor[batch * NBIN + i], c) : 0u;
    }
    __syncthreads();
    for (int i = tid; i < NBIN; i += 256) hist[i] = 0;
    __syncthreads();
    #pragma unroll
    for (int j = 0; j < 8; ++j) {
        int ix, iy, iz;
        if (point_base(q[j], ix, iy, iz)) {
            int bx0, bx1, by0, by1, bz0, bz1;
            brick_span(ix, iy, iz, bx0, bx1, by0, by1, bz0, bz1);
            for (int bz = bz0; bz <= bz1; ++bz)
                for (int by = by0; by <= by1; ++by)
                    for (int bx = bx0; bx <= bx1; ++bx) {
                        int bin = (bz * 16 + by) * 4 + bx;
                        unsigned r = atomicAdd(&hist[bin], 1u);
                        sorted[bbase[bin] + r] = q[j];
                    }
        }
    }
}

// -------- k_binsplat: one block per 32x8x4 brick; mask-gated; LDS accumulate -------
__global__ __launch_bounds__(256) void k_binsplat(const float4* __restrict__ sorted,
                                                  const unsigned* __restrict__ binStart,
                                                  const unsigned* __restrict__ gmask,
                                                  int maskon,
                                                  float* __restrict__ grid)
{
    __shared__ float brick[4 * 8 * 32];
    const int tid = threadIdx.x;
    const int bid = blockIdx.x;
    const int bx = bid & 3;
    const int by = (bid >> 2) & 15;
    const int bz = (bid >> 6) & 31;
    const int batch = bid >> 11;
    const int x0 = bx << 5, y0 = by << 3, z0 = bz << 2;

    if (maskon && gmask[batch * 64 + (bz >> 2) * 8 + (by >> 1)] == 0u) return;

    const unsigned s = binStart[bid], e = binStart[bid + 1];

    const int vx4 = tid & 7, cy = (tid >> 3) & 7, cz = tid >> 6;
    const size_t o = (size_t)batch * D3 + (size_t)(z0 + cz) * (DD * DD)
                   + (size_t)(y0 + cy) * DD + x0 + vx4 * 4;

    if (s == e) {
        *reinterpret_cast<float4*>(grid + o) = make_float4(0.f, 0.f, 0.f, 0.f);
        return;
    }

    for (int i = tid; i < 1024; i += 256) brick[i] = 0.f;
    __syncthreads();

    for (unsigned i = s + tid; i < e; i += 256) {
        float4 q = sorted[i];
        float fx = floorf(q.x), fy = floorf(q.y), fz = floorf(q.z);
        int vx = (int)fx - x0, vy = (int)fy - y0, vz = (int)fz - z0;
        float gx = q.x - fx, gy = q.y - fy, gz = q.z - fz;
        float wx0 = 1.f - gx, wy0 = 1.f - gy, wz0 = 1.f - gz;
        #pragma unroll
        for (int oz = 0; oz < 2; ++oz)
        #pragma unroll
        for (int oy = 0; oy < 2; ++oy)
        #pragma unroll
        for (int ox = 0; ox < 2; ++ox) {
            int cxx = vx + ox, cyy = vy + oy, czz = vz + oz;
            if ((unsigned)cxx < 32u && (unsigned)cyy < 8u && (unsigned)czz < 4u) {
                float w = ((ox ? gx : wx0) * (oy ? gy : wy0)) * (oz ? gz : wz0);
                atomicAdd(&brick[(czz * 8 + cyy) * 32 + cxx], q.w * w);
            }
        }
    }
    __syncthreads();

    *reinterpret_cast<float4*>(grid + o) =
        *reinterpret_cast<const float4*>(&brick[(cz * 8 + cy) * 32 + vx4 * 4]);
}

// ---------------- z blur, mask-gated: skip unmarked blocks entirely ----------------
__global__ __launch_bounds__(256) void k_blur_z(const float* __restrict__ in,
                                                float* __restrict__ out,
                                                const unsigned* __restrict__ gmask,
                                                int maskon)
{
    const int b = blockIdx.x;
    const int batch = b >> 13;
    const int z = (b >> 6) & 127;
    const int y0 = (b * 2) & 127;
    const long i = (long)b * 256 + threadIdx.x;

    unsigned okbits = 0x7fu;
    if (maskon) {
        if (gmask[batch * 64 + (z >> 4) * 8 + (y0 >> 4)] == 0u) return;
        okbits = 0u;
        #pragma unroll
        for (int j = -3; j <= 3; ++j) {
            int zj = z + j;
            if (zj >= 0 && zj < DD && gmask[batch * 64 + (zj >> 4) * 8 + (y0 >> 4)])
                okbits |= 1u << (j + 3);
        }
    }

    const double e1 = 0.6065306597126334, e2 = 0.1353352832366127, e3 = 0.011108996538242306;
    const double s = 1.0 + 2.0 * (e1 + e2 + e3);
    const float kw[7] = {(float)(e3 / s), (float)(e2 / s), (float)(e1 / s), (float)(1.0 / s),
                         (float)(e1 / s), (float)(e2 / s), (float)(e3 / s)};

    float acc = 0.f;
    #pragma unroll
    for (int j = -3; j <= 3; ++j) {
        int q = z + j;
        if (q >= 0 && q < DD && ((okbits >> (j + 3)) & 1u))
            acc = fmaf(kw[j + 3], in[i + ((long)j << 14)], acc);
    }
    out[i] = acc;
}

// ------------- fused y+x blur, mask-gated zero-fast-path + halo substitution -------
__global__ __launch_bounds__(256) void k_blur_yx(const float* __restrict__ in,
                                                 float* __restrict__ out,
                                                 const unsigned* __restrict__ gmask,
                                                 int maskon)
{
    __shared__ float sin_[38 * 128];
    __shared__ float sy[32 * 128];
    __shared__ unsigned mrow[8];

    const double e1 = 0.6065306597126334, e2 = 0.1353352832366127, e3 = 0.011108996538242306;
    const double ss = 1.0 + 2.0 * (e1 + e2 + e3);
    const float kw[7] = {(float)(e3 / ss), (float)(e2 / ss), (float)(e1 / ss), (float)(1.0 / ss),
                         (float)(e1 / ss), (float)(e2 / ss), (float)(e3 / ss)};

    const int tid = threadIdx.x;
    const int bid = blockIdx.x;
    const int ytile = bid & 3;
    const int z = (bid >> 2) & 127;
    const int batch = bid >> 9;
    const int y0 = ytile << 5;
    const size_t slab = (size_t)batch * D3 + (size_t)z * (DD * DD);

    if (maskon) {
        if (tid < 8) mrow[tid] = gmask[batch * 64 + (z >> 4) * 8 + tid];
        __syncthreads();
        const int yc0 = y0 >> 4;
        if (mrow[yc0] == 0u && mrow[yc0 + 1] == 0u) {
            const float4 z4 = make_float4(0.f, 0.f, 0.f, 0.f);
            for (int i = tid; i < 1024; i += 256) {
                int r = i >> 5, xq = i & 31;
                *reinterpret_cast<float4*>(&out[slab + (size_t)(y0 + r) * DD + xq * 4]) = z4;
            }
            return;
        }
    }

    for (int i = tid; i < 38 * 128; i += 256) {
        int row = i >> 7, xx = i & 127;
        int gy = y0 + row - 3;
        bool ok = gy >= 0 && gy < DD && (!maskon || mrow[gy >> 4]);
        sin_[i] = ok ? in[slab + (size_t)gy * DD + xx] : 0.f;
    }
    __syncthreads();

    for (int i = tid; i < 32 * 128; i += 256) {
        int r = i >> 7, xx = i & 127;
        float acc = 0.f;
        #pragma unroll
        for (int j = 0; j < 7; ++j)
            acc = fmaf(kw[j], sin_[(r + j) * 128 + xx], acc);
        sy[i] = acc;
    }
    __syncthreads();

    for (int i = tid; i < 32 * 128; i += 256) {
        int r = i >> 7, xx = i & 127;
        float acc = 0.f;
        #pragma unroll
        for (int j = -3; j <= 3; ++j) {
            int qx = xx + j;
            if (qx >= 0 && qx < DD)
                acc = fmaf(kw[j + 3], sy[r * 128 + qx], acc);
        }
        out[slab + (size_t)(y0 + r) * DD + xx] = acc;
    }
}

extern "C" void kernel_launch(void* const* d_in, const int* in_sizes, int n_in,
                              void* d_out, int out_size, void* d_ws, size_t ws_size,
                              hipStream_t stream) {
    const float* x   = (const float*)d_in[0];
    const float* w0  = (const float*)d_in[1];
    const float* b0  = (const float*)d_in[2];
    const float* w1  = (const float*)d_in[3];
    const float* b1  = (const float*)d_in[4];
    const float* w2  = (const float*)d_in[5];
    const float* b2  = (const float*)d_in[6];
    const float* w3  = (const float*)d_in[7];
    const float* b3  = (const float*)d_in[8];
    const float* w4  = (const float*)d_in[9];
    const float* b4  = (const float*)d_in[10];
    const float* wc  = (const float*)d_in[11];
    const float* bc  = (const float*)d_in[12];
    const float* wv  = (const float*)d_in[13];
    const float* bv  = (const float*)d_in[14];
    const float* c0  = (const float*)d_in[15];
    const float* v0  = (const float*)d_in[16];

    float* out = (float*)d_out;
    float4* posval = (float4*)d_out;                  // [NB][NV] float4 = 8 MiB
    float* h4 = out + 4 * 1024 * 1024;                // at +16 MiB
    float* hA = h4 + 2048;
    float* hB = hA + 2048;

    const int maskon = (ws_size >= (65ull << 20)) ? 1 : 0;
    const size_t ctrl_off = maskon ? (64ull << 20) : (48ull << 20);
    float4* sorted = (float4*)d_ws;
    unsigned* binCount  = (unsigned*)((char*)d_ws + ctrl_off);
    unsigned* gmask     = binCount + NBIN_TOT;
    unsigned* binStart  = gmask + NMASK;
    unsigned* binCursor = binStart + NBIN_TOT + 1;

    // SIREN MLP: 5 per-layer kernels, 4 blocks x 1024 threads (16-way K-split)
    k_layer<LAT, 0><<<4, 1024, 0, stream>>>(x,  w0, b0, hA);
    k_layer<HID, 1><<<4, 1024, 0, stream>>>(hA, w1, b1, hB);
    k_layer<HID, 1><<<4, 1024, 0, stream>>>(hB, w2, b2, hA);
    k_layer<HID, 1><<<4, 1024, 0, stream>>>(hA, w3, b3, hB);
    k_layer<HID, 2><<<4, 1024, 0, stream>>>(hB, w4, b4, h4);

    // heads also zeroes binCount+gmask (consumed by k_count, which runs after)
    k_heads<<<NV / 64, 256, 0, stream>>>(h4, wc, bc, wv, bv, c0, v0, posval, binCount);

    k_count<<<256, 256, 0, stream>>>(posval, binCount, gmask);
    k_scan<<<1, 1024, 0, stream>>>(binCount, binStart, binCursor);
    k_scatter<<<256, 256, 0, stream>>>(posval, binCursor, sorted);
    k_binsplat<<<NBIN_TOT, 256, 0, stream>>>(sorted, binStart, gmask, maskon, out);

    const int nblk = (NB * D3) / 256;   // 65536
    k_blur_z<<<nblk, 256, 0, stream>>>(out, (float*)d_ws, gmask, maskon);
    k_blur_yx<<<NB * 512, 256, 0, stream>>>((float*)d_ws, out, gmask, maskon);
}